// Round 4
// baseline (109.181 us; speedup 1.0000x reference)
//
#include <hip/hip_runtime.h>

#define H_DIM 768
#define B_DIM 64
#define L_DIM 512
#define M_TOT (B_DIM*L_DIM)   // 32768
#define BM 128
#define BN 128
#define BK 64
#define NB_CNT (H_DIM/BN)     // 6
#define KB_CNT (H_DIM/BK)     // 12
#define MB_CNT (M_TOT/BM)     // 256
#define TILE_HALFS (BM*BK)    // 8192 halfs = 16KB

// big-tile GEMM config
#define GBM 256
#define GMB_CNT (M_TOT/GBM)   // 128
#define BUF_HALFS 24576       // A 16384 + B 8192 halfs = 48KB
#define B_OFF 16384

typedef _Float16 f16x8 __attribute__((ext_vector_type(8)));
typedef float f32x4 __attribute__((ext_vector_type(4)));

// ws byte offsets
#define WS_W16   0u           // 768*768 halfs (tiled, swizzle-baked)
#define WS_NUP   1179648u     // 6*32768 f32
#define WS_ALPHA 1966080u     // 32768 f32
#define WS_POOL  2097152u     // 8*64*768 f32
#define WS_AIMG  3670016u     // 32768*768 halfs (tiled, swizzle-baked)
#define WS_NEED_IMG (WS_AIMG + (size_t)M_TOT*H_DIM*2)

__device__ __forceinline__ void gload_lds16(const void* g, void* l) {
  __builtin_amdgcn_global_load_lds((const __attribute__((address_space(1))) void*)g,
                                   (__attribute__((address_space(3))) void*)l, 16, 0, 0);
}

__device__ __forceinline__ f16x8 cvt8(const float* src) {
  f32x4 x0 = *(const f32x4*)src;
  f32x4 x1 = *(const f32x4*)(src + 4);
  f16x8 h;
  h[0]=(_Float16)x0[0]; h[1]=(_Float16)x0[1]; h[2]=(_Float16)x0[2]; h[3]=(_Float16)x0[3];
  h[4]=(_Float16)x1[0]; h[5]=(_Float16)x1[1]; h[6]=(_Float16)x1[2]; h[7]=(_Float16)x1[3];
  return h;
}

// tanh(v) = 1 - 2/(exp2(2.885...*v)+1); limits give +-1 exactly.
__device__ __forceinline__ float fast_tanh(float v) {
  float e = __builtin_amdgcn_exp2f(v * 2.8853900817779268f);
  return 1.0f - 2.0f * __builtin_amdgcn_rcpf(e + 1.0f);
}

// ---------------- kernel 1: W_fc fp32 -> fp16, tiled + swizzle-baked ----------------
// Tile t = nb*KB_CNT + kb holds 128x64 halfs: image[row*64 + sp*8 + j] =
//   W_fc[nb*128+row][kb*64 + (sp^(row&7))*8 + j]
__global__ __launch_bounds__(256) void wconv_kernel(const float* __restrict__ Wfc,
                                                    _Float16* __restrict__ W16) {
  int t = blockIdx.x;             // 0..71
  int nb = t / KB_CNT, kb = t % KB_CNT;
  for (int i = 0; i < 4; ++i) {
    int u = threadIdx.x + i * 256;
    int row = u >> 3, sp = u & 7;
    int sl = sp ^ (row & 7);
    *(f16x8*)(W16 + (size_t)t*TILE_HALFS + u*8) =
        cvt8(Wfc + (size_t)(nb*BN + row)*H_DIM + kb*BK + sl*8);
  }
}

// ---------------- kernel 1b: hidden_states fp32 -> fp16 tiled image ----------------
__global__ __launch_bounds__(256) void aconv_kernel(const float* __restrict__ A,
                                                    _Float16* __restrict__ img) {
  int t = blockIdx.x;             // 0..3071
  int mb = t / KB_CNT, kb = t % KB_CNT;
  _Float16* tile = img + (size_t)t * TILE_HALFS;
  for (int i = 0; i < 4; ++i) {
    int u = threadIdx.x + i * 256;
    int row = u >> 3, sp = u & 7;
    int sl = sp ^ (row & 7);
    *(f16x8*)(tile + u*8) =
        cvt8(A + (size_t)(mb*BM + row)*H_DIM + kb*BK + sl*8);
  }
}

// ---------------- big-tile GEMM helpers ----------------
// stage one K-tile (A: two 128-row image tiles, B: one) -> 6 gload_lds per wave
__device__ __forceinline__ void stage256(const _Float16* a0, const _Float16* a1,
                                         const _Float16* wt, _Float16* Lb, int tid) {
  gload_lds16(a0 + tid*8,          Lb + tid*8);
  gload_lds16(a0 + (tid+512)*8,    Lb + (tid+512)*8);
  gload_lds16(a1 + tid*8,          Lb + 8192 + tid*8);
  gload_lds16(a1 + (tid+512)*8,    Lb + 8192 + (tid+512)*8);
  gload_lds16(wt + tid*8,          Lb + B_OFF + tid*8);
  gload_lds16(wt + (tid+512)*8,    Lb + B_OFF + (tid+512)*8);
}

__device__ __forceinline__ void compute256(const _Float16* Lb, f32x4 acc[4][4],
                                           int wr, int wc, int lrow, int lk) {
#pragma unroll
  for (int kk = 0; kk < 2; ++kk) {
    f16x8 af[4], bf[4];
    int s = kk*4 + lk;
#pragma unroll
    for (int mi = 0; mi < 4; ++mi) {
      int r = wr*64 + mi*16 + lrow;                       // 0..255
      int off = (r>>7)*8192 + (r&127)*64 + ((s ^ (r & 7)) * 8);
      af[mi] = *(const f16x8*)(Lb + off);
    }
#pragma unroll
    for (int ni = 0; ni < 4; ++ni) {
      int rb = wc*64 + ni*16 + lrow;                      // 0..127
      bf[ni] = *(const f16x8*)(Lb + B_OFF + rb*64 + ((s ^ (rb & 7)) * 8));
    }
    __builtin_amdgcn_s_setprio(1);
#pragma unroll
    for (int mi = 0; mi < 4; ++mi)
#pragma unroll
      for (int ni = 0; ni < 4; ++ni)
        acc[mi][ni] = __builtin_amdgcn_mfma_f32_16x16x32_f16(af[mi], bf[ni], acc[mi][ni], 0, 0, 0);
    __builtin_amdgcn_s_setprio(0);
  }
}

// ---------------- kernel 2: 3-deep-pipelined 256x128 GEMM + tanh + dot(W_nu) ----------------
__global__ __launch_bounds__(512, 2) void gemm_nu_img_kernel(const _Float16* __restrict__ Aimg,
                                                             const _Float16* __restrict__ W16,
                                                             const float* __restrict__ bfc,
                                                             const float* __restrict__ wnu,
                                                             float* __restrict__ nup) {
  __shared__ __align__(16) _Float16 LS[3 * BUF_HALFS];    // 144KB ring
  __shared__ float nred[2][GBM];

  int bid = blockIdx.x;
  int mb = bid & (GMB_CNT - 1);   // 0..127; mb-major within nb
  int nb = bid >> 7;              // 0..5
  int m0 = mb * GBM, n0 = nb * BN;
  int tid = threadIdx.x;
  int wv = tid >> 6, ln = tid & 63;
  int wr = wv >> 1, wc = wv & 1;  // 4M x 2N wave grid, 64x64 output each
  int lrow = ln & 15, lk = ln >> 4;

  f32x4 acc[4][4] = {};
  const _Float16* a0b = Aimg + (size_t)((2*mb)   * KB_CNT) * TILE_HALFS;
  const _Float16* a1b = Aimg + (size_t)((2*mb+1) * KB_CNT) * TILE_HALFS;
  const _Float16* wtb = W16  + (size_t)(nb * KB_CNT) * TILE_HALFS;

  // epilogue constants: load + drain so in-loop vmcnt counts stay exact
  float wn[4], bb[4];
#pragma unroll
  for (int ni = 0; ni < 4; ++ni) {
    int c = n0 + wc*64 + ni*16 + lrow;    // C/D col = lane&15 (m89-verified)
    wn[ni] = wnu[c];
    bb[ni] = bfc[c];
  }
  asm volatile("s_waitcnt vmcnt(0)" ::: "memory");

  // prologue: tiles 0,1 in flight; wait tile 0 (tile 1's 6 loads remain)
  stage256(a0b,        a1b,        wtb,        LS,             tid);
  stage256(a0b + 8192, a1b + 8192, wtb + 8192, LS + BUF_HALFS, tid);
  asm volatile("s_waitcnt vmcnt(6)" ::: "memory");
  __builtin_amdgcn_s_barrier();
  __builtin_amdgcn_sched_barrier(0);

  unsigned bc = 0, bs = 2;        // compute buf, stage buf
#pragma unroll 1
  for (int kt = 0; kt < KB_CNT - 2; ++kt) {
    int k2 = (kt + 2) * 8192;
    stage256(a0b + k2, a1b + k2, wtb + k2, LS + bs * BUF_HALFS, tid);
    compute256(LS + bc * BUF_HALFS, acc, wr, wc, lrow, lk);
    asm volatile("s_waitcnt vmcnt(6)" ::: "memory");   // t+1 landed; t+2's 6 in flight
    __builtin_amdgcn_s_barrier();
    __builtin_amdgcn_sched_barrier(0);
    bc = (bc == 2) ? 0 : bc + 1;
    bs = (bs == 2) ? 0 : bs + 1;
  }
  compute256(LS + bc * BUF_HALFS, acc, wr, wc, lrow, lk);  // tile 10
  asm volatile("s_waitcnt vmcnt(0)" ::: "memory");         // drain tile 11
  __builtin_amdgcn_s_barrier();
  __builtin_amdgcn_sched_barrier(0);
  bc = (bc == 2) ? 0 : bc + 1;
  compute256(LS + bc * BUF_HALFS, acc, wr, wc, lrow, lk);  // tile 11

  // epilogue: tanh(acc+b)*wnu, reduce over this block's 128 n-columns
#pragma unroll
  for (int mi = 0; mi < 4; ++mi) {
#pragma unroll
    for (int r = 0; r < 4; ++r) {
      float s = 0.f;
#pragma unroll
      for (int ni = 0; ni < 4; ++ni)
        s = fmaf(fast_tanh(acc[mi][ni][r] + bb[ni]), wn[ni], s);
      for (int o = 1; o < 16; o <<= 1) s += __shfl_xor(s, o, 64);
      if (lrow == 0) nred[wc][wr*64 + mi*16 + lk*4 + r] = s;  // row = (lane>>4)*4+reg
    }
  }
  __syncthreads();
  if (tid < GBM)
    nup[(size_t)nb * M_TOT + m0 + tid] = nred[0][tid] + nred[1][tid];
}

// ---------------- fallback GEMM (fp32 A, in-kernel convert, 128^2) ----------------
__global__ __launch_bounds__(256) void gemm_nu_kernel(const float* __restrict__ A,
                                                      const _Float16* __restrict__ W16,
                                                      const float* __restrict__ bfc,
                                                      const float* __restrict__ wnu,
                                                      float* __restrict__ nup) {
  __shared__ __align__(16) _Float16 lsA[TILE_HALFS];
  __shared__ __align__(16) _Float16 lsB[TILE_HALFS];
  __shared__ float nred[2][BM];

  int bid = blockIdx.x;
  int nb = bid % NB_CNT;
  int mb = bid / NB_CNT;
  int m0 = mb * BM, n0 = nb * BN;
  int tid = threadIdx.x;
  int wv = tid >> 6, ln = tid & 63;
  int wr = wv >> 1, wc = wv & 1;
  int lrow = ln & 15, lk = ln >> 4;

  f32x4 acc[4][4] = {};
  const _Float16* wbase = W16 + (size_t)(nb * KB_CNT) * TILE_HALFS;

  for (int kb = 0; kb < KB_CNT; ++kb) {
    const _Float16* wt = wbase + (size_t)kb * TILE_HALFS;
    for (int i = 0; i < 4; ++i) {
      int e = i*2048 + wv*512 + ln*8;
      gload_lds16(wt + e, lsB + e);
    }
    for (int i = 0; i < 4; ++i) {
      int u = tid + i * 256;
      int row = u >> 3, sl = u & 7;
      *(f16x8*)(lsA + row*BK + ((sl ^ (row & 7)) * 8)) =
          cvt8(A + (size_t)(m0 + row) * H_DIM + kb*BK + sl*8);
    }
    __syncthreads();
#pragma unroll
    for (int kk = 0; kk < 2; ++kk) {
      f16x8 af[4], bf[4];
      int s = kk*4 + lk;
#pragma unroll
      for (int mi = 0; mi < 4; ++mi) {
        int r = wr*64 + mi*16 + lrow;
        af[mi] = *(const f16x8*)(lsA + r*BK + ((s ^ (r & 7)) * 8));
      }
#pragma unroll
      for (int ni = 0; ni < 4; ++ni) {
        int r = wc*64 + ni*16 + lrow;
        bf[ni] = *(const f16x8*)(lsB + r*BK + ((s ^ (r & 7)) * 8));
      }
#pragma unroll
      for (int mi = 0; mi < 4; ++mi)
#pragma unroll
        for (int ni = 0; ni < 4; ++ni)
          acc[mi][ni] = __builtin_amdgcn_mfma_f32_16x16x32_f16(af[mi], bf[ni], acc[mi][ni], 0, 0, 0);
    }
    __syncthreads();
  }

  float wn[4], bb[4];
  for (int ni = 0; ni < 4; ++ni) {
    int c = n0 + wc*64 + ni*16 + lrow;
    wn[ni] = wnu[c];
    bb[ni] = bfc[c];
  }
  for (int mi = 0; mi < 4; ++mi) {
    for (int r = 0; r < 4; ++r) {
      float s = 0.f;
      for (int ni = 0; ni < 4; ++ni)
        s = fmaf(fast_tanh(acc[mi][ni][r] + bb[ni]), wn[ni], s);
      for (int o = 1; o < 16; o <<= 1) s += __shfl_xor(s, o, 64);
      if (lrow == 0) nred[wc][wr*64 + mi*16 + lk*4 + r] = s;
    }
  }
  __syncthreads();
  if (tid < BM)
    nup[(size_t)nb * M_TOT + m0 + tid] = nred[0][tid] + nred[1][tid];
}

// ---------------- kernel 3: softmax over L per batch ----------------
__global__ __launch_bounds__(512) void softmax_kernel(const float* __restrict__ nup,
                                                      float* __restrict__ alphas) {
  int b = blockIdx.x;
  int l = threadIdx.x;
  int m = b * L_DIM + l;
  float v = 0.f;
  for (int nb = 0; nb < NB_CNT; ++nb) v += nup[(size_t)nb * M_TOT + m];
  __shared__ float smax[8], ssum[8];
  int w = l >> 6, ln = l & 63;
  float mx = v;
  for (int o = 1; o < 64; o <<= 1) mx = fmaxf(mx, __shfl_xor(mx, o, 64));
  if (ln == 0) smax[w] = mx;
  __syncthreads();
  mx = smax[0];
  for (int i = 1; i < 8; ++i) mx = fmaxf(mx, smax[i]);
  float e = __expf(v - mx);
  float sm = e;
  for (int o = 1; o < 64; o <<= 1) sm += __shfl_xor(sm, o, 64);
  if (ln == 0) ssum[w] = sm;
  __syncthreads();
  float tot = 0.f;
  for (int i = 0; i < 8; ++i) tot += ssum[i];
  alphas[m] = e / tot;
}

// ---------------- pooling from fp16 A-image (halves read bytes) ----------------
// block = (b, lc): 192 threads; t -> group g=t%96 (8 h-values), row-parity rp=t/96
__global__ __launch_bounds__(192) void pool1_img_kernel(const _Float16* __restrict__ img,
                                                        const float* __restrict__ alphas,
                                                        float* __restrict__ part) {
  int b = blockIdx.x >> 3;
  int lc = blockIdx.x & 7;
  int tid = threadIdx.x;
  int g = tid % 96, rp = tid / 96;      // g: kb=g>>3, sl=g&7
  int kb = g >> 3, sl = g & 7;
  __shared__ float al[64];
  __shared__ float tmp[2][H_DIM];
  if (tid < 64) al[tid] = alphas[b * L_DIM + lc*64 + tid];
  __syncthreads();
  float s[8] = {};
  for (int l = rp; l < 64; l += 2) {
    int m = b * L_DIM + lc*64 + l;
    int mb = m >> 7, row = m & 127;
    const f16x8* src = (const f16x8*)(img + ((size_t)(mb*KB_CNT + kb))*TILE_HALFS
                                      + row*64 + ((sl ^ (row & 7)) * 8));
    f16x8 h = *src;
    float a = al[l];
#pragma unroll
    for (int j = 0; j < 8; ++j) s[j] = fmaf(a, (float)h[j], s[j]);
  }
#pragma unroll
  for (int j = 0; j < 8; ++j) tmp[rp][g*8 + j] = s[j];
  __syncthreads();
  // 192 threads x 4 h each
  float* dst = part + ((size_t)lc * B_DIM + b) * H_DIM + tid*4;
  f32x4 o;
#pragma unroll
  for (int q = 0; q < 4; ++q) o[q] = tmp[0][tid*4 + q] + tmp[1][tid*4 + q];
  *(f32x4*)dst = o;
}

// fallback pool1 on fp32 hs
__global__ __launch_bounds__(256) void pool1_kernel(const float* __restrict__ hs,
                                                    const float* __restrict__ alphas,
                                                    float* __restrict__ part) {
  int b = blockIdx.x >> 3;
  int lc = blockIdx.x & 7;
  int tid = threadIdx.x;
  __shared__ float al[64];
  if (tid < 64) al[tid] = alphas[b * L_DIM + lc*64 + tid];
  __syncthreads();
  const float* xp = hs + ((size_t)b * L_DIM + lc*64) * H_DIM;
  int h0 = tid * 3;
  float s0 = 0.f, s1 = 0.f, s2 = 0.f;
  for (int l = 0; l < 64; ++l) {
    float a = al[l];
    const float* r = xp + (size_t)l * H_DIM + h0;
    s0 += a * r[0]; s1 += a * r[1]; s2 += a * r[2];
  }
  float* dst = part + ((size_t)lc * B_DIM + b) * H_DIM + h0;
  dst[0] = s0; dst[1] = s1; dst[2] = s2;
}

__global__ __launch_bounds__(256) void pool2_kernel(const float* __restrict__ part,
                                                    float* __restrict__ out) {
  int i = blockIdx.x * 256 + threadIdx.x;
  float s = 0.f;
  for (int lc = 0; lc < 8; ++lc) s += part[(size_t)lc * (B_DIM * H_DIM) + i];
  out[i] = s;
}

extern "C" void kernel_launch(void* const* d_in, const int* in_sizes, int n_in,
                              void* d_out, int out_size, void* d_ws, size_t ws_size,
                              hipStream_t stream) {
  const float* hs  = (const float*)d_in[0];
  const float* Wfc = (const float*)d_in[1];
  const float* bfc = (const float*)d_in[2];
  const float* wnu = (const float*)d_in[3];
  float* out = (float*)d_out;
  char* ws = (char*)d_ws;
  _Float16* W16 = (_Float16*)(ws + WS_W16);
  float* nup    = (float*)(ws + WS_NUP);
  float* alphas = (float*)(ws + WS_ALPHA);
  float* part   = (float*)(ws + WS_POOL);

  wconv_kernel<<<NB_CNT * KB_CNT, 256, 0, stream>>>(Wfc, W16);
  bool img = (ws_size >= WS_NEED_IMG);
  _Float16* Aimg = (_Float16*)(ws + WS_AIMG);
  if (img) {
    aconv_kernel<<<MB_CNT * KB_CNT, 256, 0, stream>>>(hs, Aimg);
    gemm_nu_img_kernel<<<GMB_CNT * NB_CNT, 512, 0, stream>>>(Aimg, W16, bfc, wnu, nup);
  } else {
    gemm_nu_kernel<<<MB_CNT * NB_CNT, 256, 0, stream>>>(hs, W16, bfc, wnu, nup);
  }
  softmax_kernel<<<B_DIM, 512, 0, stream>>>(nup, alphas);
  if (img) {
    pool1_img_kernel<<<B_DIM * 8, 192, 0, stream>>>(Aimg, alphas, part);
  } else {
    pool1_kernel<<<B_DIM * 8, 256, 0, stream>>>(hs, alphas, part);
  }
  pool2_kernel<<<192, 256, 0, stream>>>(part, out);
}

// Round 5
// 103.460 us; speedup vs baseline: 1.0553x; 1.0553x over previous
//
#include <hip/hip_runtime.h>

#define H_DIM 768
#define B_DIM 64
#define L_DIM 512
#define M_TOT (B_DIM*L_DIM)   // 32768
#define BM 128
#define BN 128
#define BK 64
#define NB_CNT (H_DIM/BN)     // 6
#define KB_CNT (H_DIM/BK)     // 12
#define MB_CNT (M_TOT/BM)     // 256
#define TILE_HALFS (BM*BK)    // 8192 halfs = 16KB

// big-tile GEMM config
#define GBM 256
#define GMB_CNT (M_TOT/GBM)   // 128
#define BUF_HALFS 24576       // A 16384 + B 8192 halfs = 48KB
#define B_OFF 16384

typedef _Float16 f16x8 __attribute__((ext_vector_type(8)));
typedef float f32x4 __attribute__((ext_vector_type(4)));

// ws byte offsets
#define WS_W16   0u           // 768*768 halfs (tiled, swizzle-baked)
#define WS_NUP   1179648u     // 6*32768 f32
#define WS_ALPHA 1966080u     // 32768 f32
#define WS_POOL  2097152u     // 8*64*768 f32
#define WS_AIMG  3670016u     // 32768*768 halfs (tiled, swizzle-baked)
#define WS_NEED_IMG (WS_AIMG + (size_t)M_TOT*H_DIM*2)

__device__ __forceinline__ void gload_lds16(const void* g, void* l) {
  __builtin_amdgcn_global_load_lds((const __attribute__((address_space(1))) void*)g,
                                   (__attribute__((address_space(3))) void*)l, 16, 0, 0);
}

__device__ __forceinline__ f16x8 cvt8(const float* src) {
  f32x4 x0 = *(const f32x4*)src;
  f32x4 x1 = *(const f32x4*)(src + 4);
  f16x8 h;
  h[0]=(_Float16)x0[0]; h[1]=(_Float16)x0[1]; h[2]=(_Float16)x0[2]; h[3]=(_Float16)x0[3];
  h[4]=(_Float16)x1[0]; h[5]=(_Float16)x1[1]; h[6]=(_Float16)x1[2]; h[7]=(_Float16)x1[3];
  return h;
}

// tanh(v) = 1 - 2/(exp2(2.885...*v)+1); limits give +-1 exactly.
__device__ __forceinline__ float fast_tanh(float v) {
  float e = __builtin_amdgcn_exp2f(v * 2.8853900817779268f);
  return 1.0f - 2.0f * __builtin_amdgcn_rcpf(e + 1.0f);
}

#define SBAR()  do { __builtin_amdgcn_sched_barrier(0); \
                     __builtin_amdgcn_s_barrier(); \
                     __builtin_amdgcn_sched_barrier(0); } while (0)

// ---------------- kernel 1: W_fc fp32 -> fp16, tiled + swizzle-baked ----------------
__global__ __launch_bounds__(256) void wconv_kernel(const float* __restrict__ Wfc,
                                                    _Float16* __restrict__ W16) {
  int t = blockIdx.x;             // 0..71
  int nb = t / KB_CNT, kb = t % KB_CNT;
  for (int i = 0; i < 4; ++i) {
    int u = threadIdx.x + i * 256;
    int row = u >> 3, sp = u & 7;
    int sl = sp ^ (row & 7);
    *(f16x8*)(W16 + (size_t)t*TILE_HALFS + u*8) =
        cvt8(Wfc + (size_t)(nb*BN + row)*H_DIM + kb*BK + sl*8);
  }
}

// ---------------- kernel 1b: hidden_states fp32 -> fp16 tiled image ----------------
__global__ __launch_bounds__(256) void aconv_kernel(const float* __restrict__ A,
                                                    _Float16* __restrict__ img) {
  int t = blockIdx.x;             // 0..3071
  int mb = t / KB_CNT, kb = t % KB_CNT;
  _Float16* tile = img + (size_t)t * TILE_HALFS;
  for (int i = 0; i < 4; ++i) {
    int u = threadIdx.x + i * 256;
    int row = u >> 3, sp = u & 7;
    int sl = sp ^ (row & 7);
    *(f16x8*)(tile + u*8) =
        cvt8(A + (size_t)(mb*BM + row)*H_DIM + kb*BK + sl*8);
  }
}

// ---------------- big-tile GEMM helpers ----------------
// stage one K-tile (A: two 128-row image tiles, B: one) -> 6 gload_lds per thread
__device__ __forceinline__ void stage256(const _Float16* a0, const _Float16* a1,
                                         const _Float16* wt, _Float16* Lb, int tid) {
  gload_lds16(a0 + tid*8,          Lb + tid*8);
  gload_lds16(a0 + (tid+512)*8,    Lb + (tid+512)*8);
  gload_lds16(a1 + tid*8,          Lb + 8192 + tid*8);
  gload_lds16(a1 + (tid+512)*8,    Lb + 8192 + (tid+512)*8);
  gload_lds16(wt + tid*8,          Lb + B_OFF + tid*8);
  gload_lds16(wt + (tid+512)*8,    Lb + B_OFF + (tid+512)*8);
}

__device__ __forceinline__ void rd_frags(const _Float16* base, const int aoff[4],
                                         const int boff[4], int slot,
                                         f16x8 af[4], f16x8 bf[4]) {
#pragma unroll
  for (int mi = 0; mi < 4; ++mi) af[mi] = *(const f16x8*)(base + aoff[mi] + slot);
#pragma unroll
  for (int ni = 0; ni < 4; ++ni) bf[ni] = *(const f16x8*)(base + boff[ni] + slot);
}

__device__ __forceinline__ void mfma16(const f16x8 af[4], const f16x8 bf[4],
                                       f32x4 acc[4][4]) {
  __builtin_amdgcn_s_setprio(1);
#pragma unroll
  for (int mi = 0; mi < 4; ++mi)
#pragma unroll
    for (int ni = 0; ni < 4; ++ni)
      acc[mi][ni] = __builtin_amdgcn_mfma_f32_16x16x32_f16(af[mi], bf[ni], acc[mi][ni], 0, 0, 0);
  __builtin_amdgcn_s_setprio(0);
}

// ---------------- kernel 2: fine-interleaved 2-phase-per-tile 256x128 GEMM ----------------
// Per K-tile: PhaseA = {rd kk1 || mfma kk0} lgkm(0) bar; PhaseB = {stage t+2, vmcnt(6), bar,
// rd kk0 of t+1 || mfma kk1}. Counted vmcnt keeps next tile's 6 loads in flight across barriers.
__global__ __launch_bounds__(512, 2) void gemm_nu_img_kernel(const _Float16* __restrict__ Aimg,
                                                             const _Float16* __restrict__ W16,
                                                             const float* __restrict__ bfc,
                                                             const float* __restrict__ wnu,
                                                             float* __restrict__ nup) {
  __shared__ __align__(16) _Float16 LS[2 * BUF_HALFS];    // 96KB double buffer
  __shared__ float nred[2][GBM];

  int bid = blockIdx.x;
  int mb = bid & (GMB_CNT - 1);   // mb-major within nb -> A-image L3 reuse
  int nb = bid >> 7;              // 0..5
  int m0 = mb * GBM, n0 = nb * BN;
  int tid = threadIdx.x;
  int wv = tid >> 6, ln = tid & 63;
  int wr = wv >> 1, wc = wv & 1;  // 4M x 2N wave grid, 64x64 output each
  int lrow = ln & 15, lk = ln >> 4;

  f32x4 acc[4][4] = {};
  f16x8 af0[4], bf0[4], af1[4], bf1[4];
  const _Float16* a0b = Aimg + (size_t)((2*mb)   * KB_CNT) * TILE_HALFS;
  const _Float16* a1b = Aimg + (size_t)((2*mb+1) * KB_CNT) * TILE_HALFS;
  const _Float16* wtb = W16  + (size_t)(nb * KB_CNT) * TILE_HALFS;
  _Float16* b0 = LS;
  _Float16* b1 = LS + BUF_HALFS;

  // per-thread fragment offsets (halfs); row%8 == lrow%8 for all frags
  int aoff[4], boff[4];
#pragma unroll
  for (int mi = 0; mi < 4; ++mi) {
    int r = wr*64 + mi*16 + lrow;
    aoff[mi] = (r>>7)*8192 + (r&127)*64;
  }
#pragma unroll
  for (int ni = 0; ni < 4; ++ni) {
    int rb = wc*64 + ni*16 + lrow;
    boff[ni] = B_OFF + rb*64;
  }
  int slot0 = ((0*4 + lk) ^ (lrow & 7)) * 8;
  int slot1 = ((1*4 + lk) ^ (lrow & 7)) * 8;

  // epilogue constants: materialize + drain so in-loop vmcnt counts stay exact
  float wn[4], bb[4];
#pragma unroll
  for (int ni = 0; ni < 4; ++ni) {
    int c = n0 + wc*64 + ni*16 + lrow;    // C/D col = lane&15 (m89-verified)
    wn[ni] = wnu[c];
    bb[ni] = bfc[c];
  }
  asm volatile("" :: "v"(wn[0]), "v"(wn[1]), "v"(wn[2]), "v"(wn[3]),
                     "v"(bb[0]), "v"(bb[1]), "v"(bb[2]), "v"(bb[3]));
  asm volatile("s_waitcnt vmcnt(0)" ::: "memory");

  // prologue: tiles 0,1 in flight; t0 landed (t1's 6 loads remain outstanding)
  stage256(a0b,        a1b,        wtb,        b0, tid);
  stage256(a0b + 8192, a1b + 8192, wtb + 8192, b1, tid);
  asm volatile("s_waitcnt vmcnt(6)" ::: "memory");
  SBAR();
  rd_frags(b0, aoff, boff, slot0, af0, bf0);    // t0 kk0

#pragma unroll 1
  for (int kt2 = 0; kt2 < 5; ++kt2) {
    size_t k2 = (size_t)(kt2*2 + 2) * 8192;
    size_t k3 = (size_t)(kt2*2 + 3) * 8192;
    // ---- tile kt=2*kt2 (buf0) ----
    rd_frags(b0, aoff, boff, slot1, af1, bf1);          // kk1
    mfma16(af0, bf0, acc);                              // kk0
    asm volatile("s_waitcnt lgkmcnt(0)" ::: "memory");  // reads done before overwrite
    SBAR();
    stage256(a0b + k2, a1b + k2, wtb + k2, b0, tid);    // tile kt+2 -> buf0
    asm volatile("s_waitcnt vmcnt(6)" ::: "memory");    // tile kt+1 landed
    SBAR();
    rd_frags(b1, aoff, boff, slot0, af0, bf0);          // tile kt+1 kk0
    mfma16(af1, bf1, acc);                              // tile kt kk1
    // ---- tile kt+1 (buf1) ----
    rd_frags(b1, aoff, boff, slot1, af1, bf1);          // kk1
    mfma16(af0, bf0, acc);                              // kk0
    asm volatile("s_waitcnt lgkmcnt(0)" ::: "memory");
    SBAR();
    stage256(a0b + k3, a1b + k3, wtb + k3, b1, tid);    // tile kt+3 -> buf1
    asm volatile("s_waitcnt vmcnt(6)" ::: "memory");    // tile kt+2 landed
    SBAR();
    rd_frags(b0, aoff, boff, slot0, af0, bf0);          // tile kt+2 kk0
    mfma16(af1, bf1, acc);                              // tile kt+1 kk1
  }

  // peel tiles 10, 11 (no more staging)
  rd_frags(b0, aoff, boff, slot1, af1, bf1);            // t10 kk1
  mfma16(af0, bf0, acc);                                // t10 kk0
  asm volatile("s_waitcnt vmcnt(0)" ::: "memory");      // t11 landed
  SBAR();
  rd_frags(b1, aoff, boff, slot0, af0, bf0);            // t11 kk0
  mfma16(af1, bf1, acc);                                // t10 kk1
  rd_frags(b1, aoff, boff, slot1, af1, bf1);            // t11 kk1
  mfma16(af0, bf0, acc);                                // t11 kk0
  mfma16(af1, bf1, acc);                                // t11 kk1

  // epilogue: tanh(acc+b)*wnu, reduce over this block's 128 n-columns
#pragma unroll
  for (int mi = 0; mi < 4; ++mi) {
#pragma unroll
    for (int r = 0; r < 4; ++r) {
      float s = 0.f;
#pragma unroll
      for (int ni = 0; ni < 4; ++ni)
        s = fmaf(fast_tanh(acc[mi][ni][r] + bb[ni]), wn[ni], s);
      for (int o = 1; o < 16; o <<= 1) s += __shfl_xor(s, o, 64);
      if (lrow == 0) nred[wc][wr*64 + mi*16 + lk*4 + r] = s;  // row = (lane>>4)*4+reg
    }
  }
  __syncthreads();
  if (tid < GBM)
    nup[(size_t)nb * M_TOT + m0 + tid] = nred[0][tid] + nred[1][tid];
}

// ---------------- fallback GEMM (fp32 A, in-kernel convert, 128^2) ----------------
__global__ __launch_bounds__(256) void gemm_nu_kernel(const float* __restrict__ A,
                                                      const _Float16* __restrict__ W16,
                                                      const float* __restrict__ bfc,
                                                      const float* __restrict__ wnu,
                                                      float* __restrict__ nup) {
  __shared__ __align__(16) _Float16 lsA[TILE_HALFS];
  __shared__ __align__(16) _Float16 lsB[TILE_HALFS];
  __shared__ float nred[2][BM];

  int bid = blockIdx.x;
  int nb = bid % NB_CNT;
  int mb = bid / NB_CNT;
  int m0 = mb * BM, n0 = nb * BN;
  int tid = threadIdx.x;
  int wv = tid >> 6, ln = tid & 63;
  int wr = wv >> 1, wc = wv & 1;
  int lrow = ln & 15, lk = ln >> 4;

  f32x4 acc[4][4] = {};
  const _Float16* wbase = W16 + (size_t)(nb * KB_CNT) * TILE_HALFS;

  for (int kb = 0; kb < KB_CNT; ++kb) {
    const _Float16* wt = wbase + (size_t)kb * TILE_HALFS;
    for (int i = 0; i < 4; ++i) {
      int e = i*2048 + wv*512 + ln*8;
      gload_lds16(wt + e, lsB + e);
    }
    for (int i = 0; i < 4; ++i) {
      int u = tid + i * 256;
      int row = u >> 3, sl = u & 7;
      *(f16x8*)(lsA + row*BK + ((sl ^ (row & 7)) * 8)) =
          cvt8(A + (size_t)(m0 + row) * H_DIM + kb*BK + sl*8);
    }
    __syncthreads();
#pragma unroll
    for (int kk = 0; kk < 2; ++kk) {
      f16x8 af[4], bf[4];
      int s = kk*4 + lk;
#pragma unroll
      for (int mi = 0; mi < 4; ++mi) {
        int r = wr*64 + mi*16 + lrow;
        af[mi] = *(const f16x8*)(lsA + r*BK + ((s ^ (r & 7)) * 8));
      }
#pragma unroll
      for (int ni = 0; ni < 4; ++ni) {
        int r = wc*64 + ni*16 + lrow;
        bf[ni] = *(const f16x8*)(lsB + r*BK + ((s ^ (r & 7)) * 8));
      }
#pragma unroll
      for (int mi = 0; mi < 4; ++mi)
#pragma unroll
        for (int ni = 0; ni < 4; ++ni)
          acc[mi][ni] = __builtin_amdgcn_mfma_f32_16x16x32_f16(af[mi], bf[ni], acc[mi][ni], 0, 0, 0);
    }
    __syncthreads();
  }

  float wn[4], bb[4];
  for (int ni = 0; ni < 4; ++ni) {
    int c = n0 + wc*64 + ni*16 + lrow;
    wn[ni] = wnu[c];
    bb[ni] = bfc[c];
  }
  for (int mi = 0; mi < 4; ++mi) {
    for (int r = 0; r < 4; ++r) {
      float s = 0.f;
      for (int ni = 0; ni < 4; ++ni)
        s = fmaf(fast_tanh(acc[mi][ni][r] + bb[ni]), wn[ni], s);
      for (int o = 1; o < 16; o <<= 1) s += __shfl_xor(s, o, 64);
      if (lrow == 0) nred[wc][wr*64 + mi*16 + lk*4 + r] = s;
    }
  }
  __syncthreads();
  if (tid < BM)
    nup[(size_t)nb * M_TOT + m0 + tid] = nred[0][tid] + nred[1][tid];
}

// ---------------- kernel 3: softmax over L per batch ----------------
__global__ __launch_bounds__(512) void softmax_kernel(const float* __restrict__ nup,
                                                      float* __restrict__ alphas) {
  int b = blockIdx.x;
  int l = threadIdx.x;
  int m = b * L_DIM + l;
  float v = 0.f;
  for (int nb = 0; nb < NB_CNT; ++nb) v += nup[(size_t)nb * M_TOT + m];
  __shared__ float smax[8], ssum[8];
  int w = l >> 6, ln = l & 63;
  float mx = v;
  for (int o = 1; o < 64; o <<= 1) mx = fmaxf(mx, __shfl_xor(mx, o, 64));
  if (ln == 0) smax[w] = mx;
  __syncthreads();
  mx = smax[0];
  for (int i = 1; i < 8; ++i) mx = fmaxf(mx, smax[i]);
  float e = __expf(v - mx);
  float sm = e;
  for (int o = 1; o < 64; o <<= 1) sm += __shfl_xor(sm, o, 64);
  if (ln == 0) ssum[w] = sm;
  __syncthreads();
  float tot = 0.f;
  for (int i = 0; i < 8; ++i) tot += ssum[i];
  alphas[m] = e / tot;
}

// ---------------- pooling from fp16 A-image ----------------
__global__ __launch_bounds__(192) void pool1_img_kernel(const _Float16* __restrict__ img,
                                                        const float* __restrict__ alphas,
                                                        float* __restrict__ part) {
  int b = blockIdx.x >> 3;
  int lc = blockIdx.x & 7;
  int tid = threadIdx.x;
  int g = tid % 96, rp = tid / 96;
  int kb = g >> 3, sl = g & 7;
  __shared__ float al[64];
  __shared__ float tmp[2][H_DIM];
  if (tid < 64) al[tid] = alphas[b * L_DIM + lc*64 + tid];
  __syncthreads();
  float s[8] = {};
  for (int l = rp; l < 64; l += 2) {
    int m = b * L_DIM + lc*64 + l;
    int mb = m >> 7, row = m & 127;
    const f16x8* src = (const f16x8*)(img + ((size_t)(mb*KB_CNT + kb))*TILE_HALFS
                                      + row*64 + ((sl ^ (row & 7)) * 8));
    f16x8 h = *src;
    float a = al[l];
#pragma unroll
    for (int j = 0; j < 8; ++j) s[j] = fmaf(a, (float)h[j], s[j]);
  }
#pragma unroll
  for (int j = 0; j < 8; ++j) tmp[rp][g*8 + j] = s[j];
  __syncthreads();
  float* dst = part + ((size_t)lc * B_DIM + b) * H_DIM + tid*4;
  f32x4 o;
#pragma unroll
  for (int q = 0; q < 4; ++q) o[q] = tmp[0][tid*4 + q] + tmp[1][tid*4 + q];
  *(f32x4*)dst = o;
}

// fallback pool1 on fp32 hs
__global__ __launch_bounds__(256) void pool1_kernel(const float* __restrict__ hs,
                                                    const float* __restrict__ alphas,
                                                    float* __restrict__ part) {
  int b = blockIdx.x >> 3;
  int lc = blockIdx.x & 7;
  int tid = threadIdx.x;
  __shared__ float al[64];
  if (tid < 64) al[tid] = alphas[b * L_DIM + lc*64 + tid];
  __syncthreads();
  const float* xp = hs + ((size_t)b * L_DIM + lc*64) * H_DIM;
  int h0 = tid * 3;
  float s0 = 0.f, s1 = 0.f, s2 = 0.f;
  for (int l = 0; l < 64; ++l) {
    float a = al[l];
    const float* r = xp + (size_t)l * H_DIM + h0;
    s0 += a * r[0]; s1 += a * r[1]; s2 += a * r[2];
  }
  float* dst = part + ((size_t)lc * B_DIM + b) * H_DIM + h0;
  dst[0] = s0; dst[1] = s1; dst[2] = s2;
}

__global__ __launch_bounds__(256) void pool2_kernel(const float* __restrict__ part,
                                                    float* __restrict__ out) {
  int i = blockIdx.x * 256 + threadIdx.x;
  float s = 0.f;
  for (int lc = 0; lc < 8; ++lc) s += part[(size_t)lc * (B_DIM * H_DIM) + i];
  out[i] = s;
}

extern "C" void kernel_launch(void* const* d_in, const int* in_sizes, int n_in,
                              void* d_out, int out_size, void* d_ws, size_t ws_size,
                              hipStream_t stream) {
  const float* hs  = (const float*)d_in[0];
  const float* Wfc = (const float*)d_in[1];
  const float* bfc = (const float*)d_in[2];
  const float* wnu = (const float*)d_in[3];
  float* out = (float*)d_out;
  char* ws = (char*)d_ws;
  _Float16* W16 = (_Float16*)(ws + WS_W16);
  float* nup    = (float*)(ws + WS_NUP);
  float* alphas = (float*)(ws + WS_ALPHA);
  float* part   = (float*)(ws + WS_POOL);

  wconv_kernel<<<NB_CNT * KB_CNT, 256, 0, stream>>>(Wfc, W16);
  bool img = (ws_size >= WS_NEED_IMG);
  _Float16* Aimg = (_Float16*)(ws + WS_AIMG);
  if (img) {
    aconv_kernel<<<MB_CNT * KB_CNT, 256, 0, stream>>>(hs, Aimg);
    gemm_nu_img_kernel<<<GMB_CNT * NB_CNT, 512, 0, stream>>>(Aimg, W16, bfc, wnu, nup);
  } else {
    gemm_nu_kernel<<<MB_CNT * NB_CNT, 256, 0, stream>>>(hs, W16, bfc, wnu, nup);
  }
  softmax_kernel<<<B_DIM, 512, 0, stream>>>(nup, alphas);
  if (img) {
    pool1_img_kernel<<<B_DIM * 8, 192, 0, stream>>>(Aimg, alphas, part);
  } else {
    pool1_kernel<<<B_DIM * 8, 256, 0, stream>>>(hs, alphas, part);
  }
  pool2_kernel<<<192, 256, 0, stream>>>(part, out);
}

// Round 6
// 98.515 us; speedup vs baseline: 1.1083x; 1.0502x over previous
//
#include <hip/hip_runtime.h>

#define H_DIM 768
#define B_DIM 64
#define L_DIM 512
#define M_TOT (B_DIM*L_DIM)   // 32768
#define BM 128
#define BN 128
#define BK 64
#define NB_CNT (H_DIM/BN)     // 6
#define KB_CNT (H_DIM/BK)     // 12
#define MB_CNT (M_TOT/BM)     // 256
#define TILE_HALFS (BM*BK)    // 8192 halfs = 16KB
#define BUFH 16384            // halfs per LDS buffer (A 8192 + B 8192 = 32KB)

typedef _Float16 f16x8 __attribute__((ext_vector_type(8)));
typedef float f32x4 __attribute__((ext_vector_type(4)));

// ws byte offsets
#define WS_W16   0u           // 768*768 halfs (tiled, swizzle-baked)
#define WS_NUP   1179648u     // 6*32768 f32
#define WS_ALPHA 1966080u     // 32768 f32
#define WS_POOL  2097152u     // 8*64*768 f32
#define WS_AIMG  3670016u     // 32768*768 halfs (tiled, swizzle-baked)
#define WS_NEED_IMG (WS_AIMG + (size_t)M_TOT*H_DIM*2)

__device__ __forceinline__ void gload_lds16(const void* g, void* l) {
  __builtin_amdgcn_global_load_lds((const __attribute__((address_space(1))) void*)g,
                                   (__attribute__((address_space(3))) void*)l, 16, 0, 0);
}

__device__ __forceinline__ f16x8 cvt8(const float* src) {
  f32x4 x0 = *(const f32x4*)src;
  f32x4 x1 = *(const f32x4*)(src + 4);
  f16x8 h;
  h[0]=(_Float16)x0[0]; h[1]=(_Float16)x0[1]; h[2]=(_Float16)x0[2]; h[3]=(_Float16)x0[3];
  h[4]=(_Float16)x1[0]; h[5]=(_Float16)x1[1]; h[6]=(_Float16)x1[2]; h[7]=(_Float16)x1[3];
  return h;
}

// tanh(v) = 1 - 2/(exp2(2.885...*v)+1); limits give +-1 exactly.
__device__ __forceinline__ float fast_tanh(float v) {
  float e = __builtin_amdgcn_exp2f(v * 2.8853900817779268f);
  return 1.0f - 2.0f * __builtin_amdgcn_rcpf(e + 1.0f);
}

#define SBAR()  do { __builtin_amdgcn_sched_barrier(0); \
                     __builtin_amdgcn_s_barrier(); \
                     __builtin_amdgcn_sched_barrier(0); } while (0)

// ---------------- kernel 1: fused {W_fc, hidden_states} fp32 -> fp16 tiled images ----
// Tile = 128 rows x 64 K halfs: image[row*64 + sp*8 + j] = src[row][ (sp^(row&7))*8 + j ]
__global__ __launch_bounds__(256) void conv_kernel(const float* __restrict__ Wfc,
                                                   const float* __restrict__ hs,
                                                   _Float16* __restrict__ W16,
                                                   _Float16* __restrict__ Aimg) {
  int t = blockIdx.x;             // 0..71 -> W tiles; 72..3143 -> A tiles
  const float* srcb;
  _Float16* dstb;
  if (t < NB_CNT * KB_CNT) {
    int nb = t / KB_CNT, kb = t % KB_CNT;
    srcb = Wfc + (size_t)(nb*BN)*H_DIM + kb*BK;
    dstb = W16 + (size_t)t*TILE_HALFS;
  } else {
    int u = t - NB_CNT * KB_CNT;
    int mb = u / KB_CNT, kb = u % KB_CNT;
    srcb = hs + (size_t)(mb*BM)*H_DIM + kb*BK;
    dstb = Aimg + (size_t)u*TILE_HALFS;
  }
#pragma unroll
  for (int i = 0; i < 4; ++i) {
    int u = threadIdx.x + i * 256;
    int row = u >> 3, sp = u & 7;
    int sl = sp ^ (row & 7);
    *(f16x8*)(dstb + u*8) = cvt8(srcb + (size_t)row*H_DIM + sl*8);
  }
}

// ---------------- GEMM helpers ----------------
// stage one 128x64 K-tile pair (A + B) -> 8 gload_lds per thread
__device__ __forceinline__ void stage128(const _Float16* at, const _Float16* wt,
                                         _Float16* Lb, int tid) {
#pragma unroll
  for (int i = 0; i < 4; ++i) {
    int e = (tid + i*256) * 8;
    gload_lds16(at + e, Lb + e);
  }
#pragma unroll
  for (int i = 0; i < 4; ++i) {
    int e = (tid + i*256) * 8;
    gload_lds16(wt + e, Lb + 8192 + e);
  }
}

__device__ __forceinline__ void rd_frags(const _Float16* base, const int aoff[4],
                                         const int boff[4], int slot,
                                         f16x8 af[4], f16x8 bf[4]) {
#pragma unroll
  for (int mi = 0; mi < 4; ++mi) af[mi] = *(const f16x8*)(base + aoff[mi] + slot);
#pragma unroll
  for (int ni = 0; ni < 4; ++ni) bf[ni] = *(const f16x8*)(base + boff[ni] + slot);
}

__device__ __forceinline__ void mfma16(const f16x8 af[4], const f16x8 bf[4],
                                       f32x4 acc[4][4]) {
  __builtin_amdgcn_s_setprio(1);
#pragma unroll
  for (int mi = 0; mi < 4; ++mi)
#pragma unroll
    for (int ni = 0; ni < 4; ++ni)
      acc[mi][ni] = __builtin_amdgcn_mfma_f32_16x16x32_f16(af[mi], bf[ni], acc[mi][ni], 0, 0, 0);
  __builtin_amdgcn_s_setprio(0);
}

// ---------------- kernel 2: fine-interleaved 2-phase dbuf 128x128 GEMM, 2 blocks/CU ----
__global__ __launch_bounds__(256, 2) void gemm_nu_img_kernel(const _Float16* __restrict__ Aimg,
                                                             const _Float16* __restrict__ W16,
                                                             const float* __restrict__ bfc,
                                                             const float* __restrict__ wnu,
                                                             float* __restrict__ nup) {
  __shared__ __align__(16) _Float16 LS[2 * BUFH];         // 64KB double buffer
  __shared__ float nred[2][BM];

  int bid = blockIdx.x;
  int mb = bid & (MB_CNT - 1);    // mb-major within nb -> A-image L3 reuse
  int nb = bid >> 8;              // 0..5
  int m0 = mb * BM, n0 = nb * BN;
  int tid = threadIdx.x;
  int wv = tid >> 6, ln = tid & 63;
  int wr = wv >> 1, wc = wv & 1;  // 2x2 wave grid, 64x64 output each
  int lrow = ln & 15, lk = ln >> 4;

  f32x4 acc[4][4] = {};
  f16x8 af0[4], bf0[4], af1[4], bf1[4];
  const _Float16* abase = Aimg + (size_t)(mb * KB_CNT) * TILE_HALFS;
  const _Float16* wbase = W16  + (size_t)(nb * KB_CNT) * TILE_HALFS;
  _Float16* b0 = LS;
  _Float16* b1 = LS + BUFH;

  // per-thread fragment offsets (halfs); frag row % 8 == lrow % 8
  int aoff[4], boff[4];
#pragma unroll
  for (int mi = 0; mi < 4; ++mi) aoff[mi] = (wr*64 + mi*16 + lrow) * 64;
#pragma unroll
  for (int ni = 0; ni < 4; ++ni) boff[ni] = 8192 + (wc*64 + ni*16 + lrow) * 64;
  int slot0 = ((0*4 + lk) ^ (lrow & 7)) * 8;
  int slot1 = ((1*4 + lk) ^ (lrow & 7)) * 8;

  // epilogue constants: materialize + drain so in-loop vmcnt counts stay exact
  float wn[4], bb[4];
#pragma unroll
  for (int ni = 0; ni < 4; ++ni) {
    int c = n0 + wc*64 + ni*16 + lrow;    // C/D col = lane&15 (m89-verified)
    wn[ni] = wnu[c];
    bb[ni] = bfc[c];
  }
  asm volatile("" :: "v"(wn[0]), "v"(wn[1]), "v"(wn[2]), "v"(wn[3]),
                     "v"(bb[0]), "v"(bb[1]), "v"(bb[2]), "v"(bb[3]));
  asm volatile("s_waitcnt vmcnt(0)" ::: "memory");

  // prologue: tiles 0,1 in flight; t0 landed (t1's 8 loads remain outstanding)
  stage128(abase,              wbase,              b0, tid);
  stage128(abase + TILE_HALFS, wbase + TILE_HALFS, b1, tid);
  asm volatile("s_waitcnt vmcnt(8)" ::: "memory");
  SBAR();
  rd_frags(b0, aoff, boff, slot0, af0, bf0);    // t0 kk0

#pragma unroll 1
  for (int kt2 = 0; kt2 < 5; ++kt2) {
    const _Float16* a2 = abase + (size_t)(kt2*2 + 2) * TILE_HALFS;
    const _Float16* w2 = wbase + (size_t)(kt2*2 + 2) * TILE_HALFS;
    const _Float16* a3 = abase + (size_t)(kt2*2 + 3) * TILE_HALFS;
    const _Float16* w3 = wbase + (size_t)(kt2*2 + 3) * TILE_HALFS;
    // ---- tile even (buf0) ----
    rd_frags(b0, aoff, boff, slot1, af1, bf1);          // kk1
    mfma16(af0, bf0, acc);                              // kk0
    asm volatile("s_waitcnt lgkmcnt(0)" ::: "memory");  // b0 fully read
    SBAR();
    stage128(a2, w2, b0, tid);                          // tile t+2 -> b0
    asm volatile("s_waitcnt vmcnt(8)" ::: "memory");    // tile t+1 landed
    SBAR();
    rd_frags(b1, aoff, boff, slot0, af0, bf0);          // t+1 kk0
    mfma16(af1, bf1, acc);                              // t kk1
    // ---- tile odd (buf1) ----
    rd_frags(b1, aoff, boff, slot1, af1, bf1);          // kk1
    mfma16(af0, bf0, acc);                              // kk0
    asm volatile("s_waitcnt lgkmcnt(0)" ::: "memory");  // b1 fully read
    SBAR();
    stage128(a3, w3, b1, tid);                          // tile t+3 -> b1
    asm volatile("s_waitcnt vmcnt(8)" ::: "memory");    // tile t+2 landed
    SBAR();
    rd_frags(b0, aoff, boff, slot0, af0, bf0);          // t+2 kk0
    mfma16(af1, bf1, acc);                              // t+1 kk1
  }

  // peel tiles 10 (b0), 11 (b1) — no more staging
  rd_frags(b0, aoff, boff, slot1, af1, bf1);            // t10 kk1
  mfma16(af0, bf0, acc);                                // t10 kk0
  asm volatile("s_waitcnt vmcnt(0)" ::: "memory");      // t11 landed
  SBAR();
  rd_frags(b1, aoff, boff, slot0, af0, bf0);            // t11 kk0
  mfma16(af1, bf1, acc);                                // t10 kk1
  rd_frags(b1, aoff, boff, slot1, af1, bf1);            // t11 kk1
  mfma16(af0, bf0, acc);                                // t11 kk0
  mfma16(af1, bf1, acc);                                // t11 kk1

  // epilogue: tanh(acc+b)*wnu, reduce over this block's 128 n-columns
#pragma unroll
  for (int mi = 0; mi < 4; ++mi) {
#pragma unroll
    for (int r = 0; r < 4; ++r) {
      float s = 0.f;
#pragma unroll
      for (int ni = 0; ni < 4; ++ni)
        s = fmaf(fast_tanh(acc[mi][ni][r] + bb[ni]), wn[ni], s);
      for (int o = 1; o < 16; o <<= 1) s += __shfl_xor(s, o, 64);
      if (lrow == 0) nred[wc][wr*64 + mi*16 + lk*4 + r] = s;  // row = (lane>>4)*4+reg
    }
  }
  __syncthreads();
  if (tid < BM)
    nup[(size_t)nb * M_TOT + m0 + tid] = nred[0][tid] + nred[1][tid];
}

// ---------------- fallback GEMM (fp32 A, in-kernel convert, 128^2) ----------------
__global__ __launch_bounds__(256) void gemm_nu_kernel(const float* __restrict__ A,
                                                      const _Float16* __restrict__ W16,
                                                      const float* __restrict__ bfc,
                                                      const float* __restrict__ wnu,
                                                      float* __restrict__ nup) {
  __shared__ __align__(16) _Float16 lsA[TILE_HALFS];
  __shared__ __align__(16) _Float16 lsB[TILE_HALFS];
  __shared__ float nred[2][BM];

  int bid = blockIdx.x;
  int nb = bid % NB_CNT;
  int mb = bid / NB_CNT;
  int m0 = mb * BM, n0 = nb * BN;
  int tid = threadIdx.x;
  int wv = tid >> 6, ln = tid & 63;
  int wr = wv >> 1, wc = wv & 1;
  int lrow = ln & 15, lk = ln >> 4;

  f32x4 acc[4][4] = {};
  const _Float16* wbase = W16 + (size_t)(nb * KB_CNT) * TILE_HALFS;

  for (int kb = 0; kb < KB_CNT; ++kb) {
    const _Float16* wt = wbase + (size_t)kb * TILE_HALFS;
    for (int i = 0; i < 4; ++i) {
      int e = (tid + i*256) * 8;
      gload_lds16(wt + e, lsB + e);
    }
    for (int i = 0; i < 4; ++i) {
      int u = tid + i * 256;
      int row = u >> 3, sl = u & 7;
      *(f16x8*)(lsA + row*BK + ((sl ^ (row & 7)) * 8)) =
          cvt8(A + (size_t)(m0 + row) * H_DIM + kb*BK + sl*8);
    }
    __syncthreads();
#pragma unroll
    for (int kk = 0; kk < 2; ++kk) {
      f16x8 af[4], bf[4];
      int s = kk*4 + lk;
#pragma unroll
      for (int mi = 0; mi < 4; ++mi) {
        int r = wr*64 + mi*16 + lrow;
        af[mi] = *(const f16x8*)(lsA + r*BK + ((s ^ (r & 7)) * 8));
      }
#pragma unroll
      for (int ni = 0; ni < 4; ++ni) {
        int r = wc*64 + ni*16 + lrow;
        bf[ni] = *(const f16x8*)(lsB + r*BK + ((s ^ (r & 7)) * 8));
      }
#pragma unroll
      for (int mi = 0; mi < 4; ++mi)
#pragma unroll
        for (int ni = 0; ni < 4; ++ni)
          acc[mi][ni] = __builtin_amdgcn_mfma_f32_16x16x32_f16(af[mi], bf[ni], acc[mi][ni], 0, 0, 0);
    }
    __syncthreads();
  }

  float wn[4], bb[4];
  for (int ni = 0; ni < 4; ++ni) {
    int c = n0 + wc*64 + ni*16 + lrow;
    wn[ni] = wnu[c];
    bb[ni] = bfc[c];
  }
  for (int mi = 0; mi < 4; ++mi) {
    for (int r = 0; r < 4; ++r) {
      float s = 0.f;
      for (int ni = 0; ni < 4; ++ni)
        s = fmaf(fast_tanh(acc[mi][ni][r] + bb[ni]), wn[ni], s);
      for (int o = 1; o < 16; o <<= 1) s += __shfl_xor(s, o, 64);
      if (lrow == 0) nred[wc][wr*64 + mi*16 + lk*4 + r] = s;
    }
  }
  __syncthreads();
  if (tid < BM)
    nup[(size_t)nb * M_TOT + m0 + tid] = nred[0][tid] + nred[1][tid];
}

// ---------------- kernel 3: softmax over L per batch ----------------
__global__ __launch_bounds__(512) void softmax_kernel(const float* __restrict__ nup,
                                                      float* __restrict__ alphas) {
  int b = blockIdx.x;
  int l = threadIdx.x;
  int m = b * L_DIM + l;
  float v = 0.f;
  for (int nb = 0; nb < NB_CNT; ++nb) v += nup[(size_t)nb * M_TOT + m];
  __shared__ float smax[8], ssum[8];
  int w = l >> 6, ln = l & 63;
  float mx = v;
  for (int o = 1; o < 64; o <<= 1) mx = fmaxf(mx, __shfl_xor(mx, o, 64));
  if (ln == 0) smax[w] = mx;
  __syncthreads();
  mx = smax[0];
  for (int i = 1; i < 8; ++i) mx = fmaxf(mx, smax[i]);
  float e = __expf(v - mx);
  float sm = e;
  for (int o = 1; o < 64; o <<= 1) sm += __shfl_xor(sm, o, 64);
  if (ln == 0) ssum[w] = sm;
  __syncthreads();
  float tot = 0.f;
  for (int i = 0; i < 8; ++i) tot += ssum[i];
  alphas[m] = e / tot;
}

// ---------------- pooling from fp16 A-image ----------------
__global__ __launch_bounds__(192) void pool1_img_kernel(const _Float16* __restrict__ img,
                                                        const float* __restrict__ alphas,
                                                        float* __restrict__ part) {
  int b = blockIdx.x >> 3;
  int lc = blockIdx.x & 7;
  int tid = threadIdx.x;
  int g = tid % 96, rp = tid / 96;
  int kb = g >> 3, sl = g & 7;
  __shared__ float al[64];
  __shared__ float tmp[2][H_DIM];
  if (tid < 64) al[tid] = alphas[b * L_DIM + lc*64 + tid];
  __syncthreads();
  float s[8] = {};
  for (int l = rp; l < 64; l += 2) {
    int m = b * L_DIM + lc*64 + l;
    int mb = m >> 7, row = m & 127;
    const f16x8* src = (const f16x8*)(img + ((size_t)(mb*KB_CNT + kb))*TILE_HALFS
                                      + row*64 + ((sl ^ (row & 7)) * 8));
    f16x8 h = *src;
    float a = al[l];
#pragma unroll
    for (int j = 0; j < 8; ++j) s[j] = fmaf(a, (float)h[j], s[j]);
  }
#pragma unroll
  for (int j = 0; j < 8; ++j) tmp[rp][g*8 + j] = s[j];
  __syncthreads();
  float* dst = part + ((size_t)lc * B_DIM + b) * H_DIM + tid*4;
  f32x4 o;
#pragma unroll
  for (int q = 0; q < 4; ++q) o[q] = tmp[0][tid*4 + q] + tmp[1][tid*4 + q];
  *(f32x4*)dst = o;
}

// fallback pool1 on fp32 hs
__global__ __launch_bounds__(256) void pool1_kernel(const float* __restrict__ hs,
                                                    const float* __restrict__ alphas,
                                                    float* __restrict__ part) {
  int b = blockIdx.x >> 3;
  int lc = blockIdx.x & 7;
  int tid = threadIdx.x;
  __shared__ float al[64];
  if (tid < 64) al[tid] = alphas[b * L_DIM + lc*64 + tid];
  __syncthreads();
  const float* xp = hs + ((size_t)b * L_DIM + lc*64) * H_DIM;
  int h0 = tid * 3;
  float s0 = 0.f, s1 = 0.f, s2 = 0.f;
  for (int l = 0; l < 64; ++l) {
    float a = al[l];
    const float* r = xp + (size_t)l * H_DIM + h0;
    s0 += a * r[0]; s1 += a * r[1]; s2 += a * r[2];
  }
  float* dst = part + ((size_t)lc * B_DIM + b) * H_DIM + h0;
  dst[0] = s0; dst[1] = s1; dst[2] = s2;
}

__global__ __launch_bounds__(256) void pool2_kernel(const float* __restrict__ part,
                                                    float* __restrict__ out) {
  int i = blockIdx.x * 256 + threadIdx.x;
  float s = 0.f;
  for (int lc = 0; lc < 8; ++lc) s += part[(size_t)lc * (B_DIM * H_DIM) + i];
  out[i] = s;
}

extern "C" void kernel_launch(void* const* d_in, const int* in_sizes, int n_in,
                              void* d_out, int out_size, void* d_ws, size_t ws_size,
                              hipStream_t stream) {
  const float* hs  = (const float*)d_in[0];
  const float* Wfc = (const float*)d_in[1];
  const float* bfc = (const float*)d_in[2];
  const float* wnu = (const float*)d_in[3];
  float* out = (float*)d_out;
  char* ws = (char*)d_ws;
  _Float16* W16 = (_Float16*)(ws + WS_W16);
  float* nup    = (float*)(ws + WS_NUP);
  float* alphas = (float*)(ws + WS_ALPHA);
  float* part   = (float*)(ws + WS_POOL);

  bool img = (ws_size >= WS_NEED_IMG);
  _Float16* Aimg = (_Float16*)(ws + WS_AIMG);
  if (img) {
    conv_kernel<<<(NB_CNT + MB_CNT) * KB_CNT, 256, 0, stream>>>(Wfc, hs, W16, Aimg);
    gemm_nu_img_kernel<<<MB_CNT * NB_CNT, 256, 0, stream>>>(Aimg, W16, bfc, wnu, nup);
  } else {
    conv_kernel<<<NB_CNT * KB_CNT, 256, 0, stream>>>(Wfc, hs, W16, Aimg);
    gemm_nu_kernel<<<MB_CNT * NB_CNT, 256, 0, stream>>>(hs, W16, bfc, wnu, nup);
  }
  softmax_kernel<<<B_DIM, 512, 0, stream>>>(nup, alphas);
  if (img) {
    pool1_img_kernel<<<B_DIM * 8, 192, 0, stream>>>(Aimg, alphas, part);
  } else {
    pool1_kernel<<<B_DIM * 8, 256, 0, stream>>>(hs, alphas, part);
  }
  pool2_kernel<<<192, 256, 0, stream>>>(part, out);
}

// Round 7
// 91.828 us; speedup vs baseline: 1.1890x; 1.0728x over previous
//
#include <hip/hip_runtime.h>

#define H_DIM 768
#define B_DIM 64
#define L_DIM 512
#define M_TOT (B_DIM*L_DIM)   // 32768
#define BM 128
#define BN 128
#define BK 64
#define NB_CNT (H_DIM/BN)     // 6
#define KB_CNT (H_DIM/BK)     // 12
#define MB_CNT (M_TOT/BM)     // 256
#define TILE_HALFS (BM*BK)    // 8192 halfs = 16KB
#define BUFH 16384            // halfs per LDS buffer (A 8192 + B 8192 = 32KB)

typedef _Float16 f16x8 __attribute__((ext_vector_type(8)));
typedef float f32x4 __attribute__((ext_vector_type(4)));

// ws byte offsets
#define WS_W16   0u           // 768*768 halfs (tiled, swizzle-baked)
#define WS_NUP   1179648u     // 6*32768 f32
#define WS_ALPHA 1966080u     // 32768 f32
#define WS_POOL  2097152u     // 8*64*768 f32
#define WS_AIMG  3670016u     // 32768*768 halfs (tiled, swizzle-baked)
#define WS_NEED_IMG (WS_AIMG + (size_t)M_TOT*H_DIM*2)

__device__ __forceinline__ void gload_lds16(const void* g, void* l) {
  __builtin_amdgcn_global_load_lds((const __attribute__((address_space(1))) void*)g,
                                   (__attribute__((address_space(3))) void*)l, 16, 0, 0);
}

__device__ __forceinline__ f16x8 cvt8(const float* src) {
  f32x4 x0 = *(const f32x4*)src;
  f32x4 x1 = *(const f32x4*)(src + 4);
  f16x8 h;
  h[0]=(_Float16)x0[0]; h[1]=(_Float16)x0[1]; h[2]=(_Float16)x0[2]; h[3]=(_Float16)x0[3];
  h[4]=(_Float16)x1[0]; h[5]=(_Float16)x1[1]; h[6]=(_Float16)x1[2]; h[7]=(_Float16)x1[3];
  return h;
}

// tanh(v) = 1 - 2/(exp2(2.885...*v)+1); limits give +-1 exactly.
__device__ __forceinline__ float fast_tanh(float v) {
  float e = __builtin_amdgcn_exp2f(v * 2.8853900817779268f);
  return 1.0f - 2.0f * __builtin_amdgcn_rcpf(e + 1.0f);
}

#define SBAR()  do { __builtin_amdgcn_sched_barrier(0); \
                     __builtin_amdgcn_s_barrier(); \
                     __builtin_amdgcn_sched_barrier(0); } while (0)

// ---------------- kernel 1: fused {W_fc, hidden_states} fp32 -> fp16 tiled images ----
__global__ __launch_bounds__(256) void conv_kernel(const float* __restrict__ Wfc,
                                                   const float* __restrict__ hs,
                                                   _Float16* __restrict__ W16,
                                                   _Float16* __restrict__ Aimg) {
  int t = blockIdx.x;             // 0..71 -> W tiles; 72..3143 -> A tiles
  const float* srcb;
  _Float16* dstb;
  if (t < NB_CNT * KB_CNT) {
    int nb = t / KB_CNT, kb = t % KB_CNT;
    srcb = Wfc + (size_t)(nb*BN)*H_DIM + kb*BK;
    dstb = W16 + (size_t)t*TILE_HALFS;
  } else {
    int u = t - NB_CNT * KB_CNT;
    int mb = u / KB_CNT, kb = u % KB_CNT;
    srcb = hs + (size_t)(mb*BM)*H_DIM + kb*BK;
    dstb = Aimg + (size_t)u*TILE_HALFS;
  }
#pragma unroll
  for (int i = 0; i < 4; ++i) {
    int u = threadIdx.x + i * 256;
    int row = u >> 3, sp = u & 7;
    int sl = sp ^ (row & 7);
    *(f16x8*)(dstb + u*8) = cvt8(srcb + (size_t)row*H_DIM + sl*8);
  }
}

// ---------------- GEMM helpers ----------------
__device__ __forceinline__ void stage128(const _Float16* at, const _Float16* wt,
                                         _Float16* Lb, int tid) {
#pragma unroll
  for (int i = 0; i < 4; ++i) {
    int e = (tid + i*256) * 8;
    gload_lds16(at + e, Lb + e);
  }
#pragma unroll
  for (int i = 0; i < 4; ++i) {
    int e = (tid + i*256) * 8;
    gload_lds16(wt + e, Lb + 8192 + e);
  }
}

__device__ __forceinline__ void rd_frags(const _Float16* base, const int aoff[4],
                                         const int boff[4], int slot,
                                         f16x8 af[4], f16x8 bf[4]) {
#pragma unroll
  for (int mi = 0; mi < 4; ++mi) af[mi] = *(const f16x8*)(base + aoff[mi] + slot);
#pragma unroll
  for (int ni = 0; ni < 4; ++ni) bf[ni] = *(const f16x8*)(base + boff[ni] + slot);
}

__device__ __forceinline__ void mfma16(const f16x8 af[4], const f16x8 bf[4],
                                       f32x4 acc[4][4]) {
  __builtin_amdgcn_s_setprio(1);
#pragma unroll
  for (int mi = 0; mi < 4; ++mi)
#pragma unroll
    for (int ni = 0; ni < 4; ++ni)
      acc[mi][ni] = __builtin_amdgcn_mfma_f32_16x16x32_f16(af[mi], bf[ni], acc[mi][ni], 0, 0, 0);
  __builtin_amdgcn_s_setprio(0);
}

// One pipelined iteration for tile j of a pass (P compile-time after unroll).
// Stages tile T+2 (wraps into next pass), counted vmcnt keeps 8 loads in flight.
#define PASS_ITER(P, j) do {                                                   \
    _Float16* bufc_ = ((j) & 1) ? b1 : b0;                                     \
    _Float16* bufn_ = ((j) & 1) ? b0 : b1;                                     \
    rd_frags(bufc_, aoff, boff, slot1, af1, bf1);                              \
    mfma16(af0, bf0, acc);                                                     \
    asm volatile("s_waitcnt lgkmcnt(0)" ::: "memory");                         \
    SBAR();                                                                    \
    if ((P) < 2 || (j) < 10) {                                                 \
      const _Float16* aS = abase + (size_t)(((j) < 10) ? (j) + 2 : (j) - 10) * TILE_HALFS; \
      stage128(aS, wS, bufc_, tid);                                            \
      wS += TILE_HALFS;                                                        \
    }                                                                          \
    if ((P) == 2 && (j) == 10) { asm volatile("s_waitcnt vmcnt(0)" ::: "memory"); } \
    else                       { asm volatile("s_waitcnt vmcnt(8)" ::: "memory"); } \
    SBAR();                                                                    \
    rd_frags(bufn_, aoff, boff, slot0, af0, bf0);                              \
    mfma16(af1, bf1, acc);                                                     \
  } while (0)

// Per-pass epilogue: tanh + wnu-dot + LDS-transpose reduction + store. Runs while
// next pass's first tiles stream in (covers their latency).
#define EPI(P) do {                                                            \
    float s16_[4][4];                                                          \
    _Pragma("unroll") for (int mi = 0; mi < 4; ++mi)                           \
    _Pragma("unroll") for (int r = 0; r < 4; ++r) {                            \
      float s_ = 0.f;                                                          \
      _Pragma("unroll") for (int ni = 0; ni < 4; ++ni)                         \
        s_ = fmaf(fast_tanh(acc[mi][ni][r] + bb[P][ni]), wn[P][ni], s_);       \
      s16_[mi][r] = s_;                                                        \
    }                                                                          \
    if (wc == 0) {                                                             \
      _Pragma("unroll") for (int mi = 0; mi < 4; ++mi)                         \
      _Pragma("unroll") for (int r = 0; r < 4; ++r)                            \
        scr[(wr*64 + mi*16 + lk*4 + r)*20 + lrow] = s16_[mi][r];               \
    }                                                                          \
    asm volatile("s_waitcnt lgkmcnt(0)" ::: "memory");                         \
    SBAR();                                                                    \
    float pa_ = 0.f;                                                           \
    if (tid < 128) {                                                           \
      const f32x4* sp_ = (const f32x4*)(scr + tid*20);                         \
      f32x4 q_ = sp_[0] + sp_[1] + sp_[2] + sp_[3];                            \
      pa_ = q_[0] + q_[1] + q_[2] + q_[3];                                     \
    }                                                                          \
    asm volatile("s_waitcnt lgkmcnt(0)" ::: "memory");                         \
    SBAR();                                                                    \
    if (wc == 1) {                                                             \
      _Pragma("unroll") for (int mi = 0; mi < 4; ++mi)                         \
      _Pragma("unroll") for (int r = 0; r < 4; ++r)                            \
        scr[(wr*64 + mi*16 + lk*4 + r)*20 + lrow] = s16_[mi][r];               \
    }                                                                          \
    asm volatile("s_waitcnt lgkmcnt(0)" ::: "memory");                         \
    SBAR();                                                                    \
    if (tid < 128) {                                                           \
      const f32x4* sp_ = (const f32x4*)(scr + tid*20);                         \
      f32x4 q_ = sp_[0] + sp_[1] + sp_[2] + sp_[3];                            \
      nup[(size_t)(nb0 + (P)) * M_TOT + m0 + tid] = pa_ + q_[0]+q_[1]+q_[2]+q_[3]; \
    }                                                                          \
  } while (0)

// ---------------- kernel 2: multi-pass (3 nb per block) pipelined 128x128 GEMM ----
__global__ __launch_bounds__(256, 2) void gemm_nu_img_kernel(const _Float16* __restrict__ Aimg,
                                                             const _Float16* __restrict__ W16,
                                                             const float* __restrict__ bfc,
                                                             const float* __restrict__ wnu,
                                                             float* __restrict__ nup) {
  __shared__ __align__(16) _Float16 LS[2 * BUFH];         // 64KB double buffer
  __shared__ __align__(16) float scr[128 * 20];           // 10KB reduce scratch

  int bid = blockIdx.x;
  int mb = bid & (MB_CNT - 1);    // 0..255
  int nb0 = (bid >> 8) * 3;       // 0 or 3
  int m0 = mb * BM;
  int tid = threadIdx.x;
  int wv = tid >> 6, ln = tid & 63;
  int wr = wv >> 1, wc = wv & 1;  // 2x2 wave grid, 64x64 output each
  int lrow = ln & 15, lk = ln >> 4;

  f32x4 acc[4][4] = {};
  f16x8 af0[4], bf0[4], af1[4], bf1[4];
  const _Float16* abase = Aimg + (size_t)(mb * KB_CNT) * TILE_HALFS;
  const _Float16* wbase = W16  + (size_t)(nb0 * KB_CNT) * TILE_HALFS;
  _Float16* b0 = LS;
  _Float16* b1 = LS + BUFH;

  // per-thread fragment offsets (halfs); frag row % 8 == lrow % 8
  int aoff[4], boff[4];
#pragma unroll
  for (int mi = 0; mi < 4; ++mi) aoff[mi] = (wr*64 + mi*16 + lrow) * 64;
#pragma unroll
  for (int ni = 0; ni < 4; ++ni) boff[ni] = 8192 + (wc*64 + ni*16 + lrow) * 64;
  int slot0 = ((0*4 + lk) ^ (lrow & 7)) * 8;
  int slot1 = ((1*4 + lk) ^ (lrow & 7)) * 8;

  // epilogue constants for all 3 passes; drain so in-loop vmcnt counts stay exact
  float wn[3][4], bb[3][4];
#pragma unroll
  for (int p = 0; p < 3; ++p)
#pragma unroll
    for (int ni = 0; ni < 4; ++ni) {
      int c = (nb0 + p)*BN + wc*64 + ni*16 + lrow;  // C/D col = lane&15 (m89-verified)
      wn[p][ni] = wnu[c];
      bb[p][ni] = bfc[c];
    }
  asm volatile("s_waitcnt vmcnt(0)" ::: "memory");

  // prologue: tiles 0,1 of pass 0 in flight; t0 landed (t1's 8 loads outstanding)
  stage128(abase,              wbase,              b0, tid);
  stage128(abase + TILE_HALFS, wbase + TILE_HALFS, b1, tid);
  const _Float16* wS = wbase + 2 * TILE_HALFS;    // W source for tile T+2 (monotonic)
  asm volatile("s_waitcnt vmcnt(8)" ::: "memory");
  SBAR();
  rd_frags(b0, aoff, boff, slot0, af0, bf0);      // t0 kk0

  // ---- pass 0 ----
#pragma unroll 1
  for (int j = 0; j < 12; ++j) PASS_ITER(0, j);
  EPI(0);
#pragma unroll
  for (int mi = 0; mi < 4; ++mi)
#pragma unroll
    for (int ni = 0; ni < 4; ++ni) acc[mi][ni] = f32x4{0.f, 0.f, 0.f, 0.f};

  // ---- pass 1 ----
#pragma unroll 1
  for (int j = 0; j < 12; ++j) PASS_ITER(1, j);
  EPI(1);
#pragma unroll
  for (int mi = 0; mi < 4; ++mi)
#pragma unroll
    for (int ni = 0; ni < 4; ++ni) acc[mi][ni] = f32x4{0.f, 0.f, 0.f, 0.f};

  // ---- pass 2 (last tile peeled) ----
#pragma unroll 1
  for (int j = 0; j < 11; ++j) PASS_ITER(2, j);
  rd_frags(b1, aoff, boff, slot1, af1, bf1);      // t35 kk1
  mfma16(af0, bf0, acc);                          // t35 kk0
  mfma16(af1, bf1, acc);                          // t35 kk1
  EPI(2);
}

// ---------------- fallback GEMM (fp32 A, in-kernel convert, 128^2) ----------------
__global__ __launch_bounds__(256) void gemm_nu_kernel(const float* __restrict__ A,
                                                      const _Float16* __restrict__ W16,
                                                      const float* __restrict__ bfc,
                                                      const float* __restrict__ wnu,
                                                      float* __restrict__ nup) {
  __shared__ __align__(16) _Float16 lsA[TILE_HALFS];
  __shared__ __align__(16) _Float16 lsB[TILE_HALFS];
  __shared__ float nred[2][BM];

  int bid = blockIdx.x;
  int nb = bid % NB_CNT;
  int mb = bid / NB_CNT;
  int m0 = mb * BM, n0 = nb * BN;
  int tid = threadIdx.x;
  int wv = tid >> 6, ln = tid & 63;
  int wr = wv >> 1, wc = wv & 1;
  int lrow = ln & 15, lk = ln >> 4;

  f32x4 acc[4][4] = {};
  const _Float16* wbase = W16 + (size_t)(nb * KB_CNT) * TILE_HALFS;

  for (int kb = 0; kb < KB_CNT; ++kb) {
    const _Float16* wt = wbase + (size_t)kb * TILE_HALFS;
    for (int i = 0; i < 4; ++i) {
      int e = (tid + i*256) * 8;
      gload_lds16(wt + e, lsB + e);
    }
    for (int i = 0; i < 4; ++i) {
      int u = tid + i * 256;
      int row = u >> 3, sl = u & 7;
      *(f16x8*)(lsA + row*BK + ((sl ^ (row & 7)) * 8)) =
          cvt8(A + (size_t)(m0 + row) * H_DIM + kb*BK + sl*8);
    }
    __syncthreads();
#pragma unroll
    for (int kk = 0; kk < 2; ++kk) {
      f16x8 af[4], bf[4];
      int s = kk*4 + lk;
#pragma unroll
      for (int mi = 0; mi < 4; ++mi) {
        int r = wr*64 + mi*16 + lrow;
        af[mi] = *(const f16x8*)(lsA + r*BK + ((s ^ (r & 7)) * 8));
      }
#pragma unroll
      for (int ni = 0; ni < 4; ++ni) {
        int r = wc*64 + ni*16 + lrow;
        bf[ni] = *(const f16x8*)(lsB + r*BK + ((s ^ (r & 7)) * 8));
      }
#pragma unroll
      for (int mi = 0; mi < 4; ++mi)
#pragma unroll
        for (int ni = 0; ni < 4; ++ni)
          acc[mi][ni] = __builtin_amdgcn_mfma_f32_16x16x32_f16(af[mi], bf[ni], acc[mi][ni], 0, 0, 0);
    }
    __syncthreads();
  }

  float wn[4], bb[4];
  for (int ni = 0; ni < 4; ++ni) {
    int c = n0 + wc*64 + ni*16 + lrow;
    wn[ni] = wnu[c];
    bb[ni] = bfc[c];
  }
  for (int mi = 0; mi < 4; ++mi) {
    for (int r = 0; r < 4; ++r) {
      float s = 0.f;
      for (int ni = 0; ni < 4; ++ni)
        s = fmaf(fast_tanh(acc[mi][ni][r] + bb[ni]), wn[ni], s);
      for (int o = 1; o < 16; o <<= 1) s += __shfl_xor(s, o, 64);
      if (lrow == 0) nred[wc][wr*64 + mi*16 + lk*4 + r] = s;
    }
  }
  __syncthreads();
  if (tid < BM)
    nup[(size_t)nb * M_TOT + m0 + tid] = nred[0][tid] + nred[1][tid];
}

// ---------------- kernel 3: softmax over L per batch ----------------
__global__ __launch_bounds__(512) void softmax_kernel(const float* __restrict__ nup,
                                                      float* __restrict__ alphas) {
  int b = blockIdx.x;
  int l = threadIdx.x;
  int m = b * L_DIM + l;
  float v = 0.f;
  for (int nb = 0; nb < NB_CNT; ++nb) v += nup[(size_t)nb * M_TOT + m];
  __shared__ float smax[8], ssum[8];
  int w = l >> 6, ln = l & 63;
  float mx = v;
  for (int o = 1; o < 64; o <<= 1) mx = fmaxf(mx, __shfl_xor(mx, o, 64));
  if (ln == 0) smax[w] = mx;
  __syncthreads();
  mx = smax[0];
  for (int i = 1; i < 8; ++i) mx = fmaxf(mx, smax[i]);
  float e = __expf(v - mx);
  float sm = e;
  for (int o = 1; o < 64; o <<= 1) sm += __shfl_xor(sm, o, 64);
  if (ln == 0) ssum[w] = sm;
  __syncthreads();
  float tot = 0.f;
  for (int i = 0; i < 8; ++i) tot += ssum[i];
  alphas[m] = e / tot;
}

// ---------------- pooling from fp16 A-image ----------------
__global__ __launch_bounds__(192) void pool1_img_kernel(const _Float16* __restrict__ img,
                                                        const float* __restrict__ alphas,
                                                        float* __restrict__ part) {
  int b = blockIdx.x >> 3;
  int lc = blockIdx.x & 7;
  int tid = threadIdx.x;
  int g = tid % 96, rp = tid / 96;
  int kb = g >> 3, sl = g & 7;
  __shared__ float al[64];
  __shared__ float tmp[2][H_DIM];
  if (tid < 64) al[tid] = alphas[b * L_DIM + lc*64 + tid];
  __syncthreads();
  float s[8] = {};
  for (int l = rp; l < 64; l += 2) {
    int m = b * L_DIM + lc*64 + l;
    int mb = m >> 7, row = m & 127;
    const f16x8* src = (const f16x8*)(img + ((size_t)(mb*KB_CNT + kb))*TILE_HALFS
                                      + row*64 + ((sl ^ (row & 7)) * 8));
    f16x8 h = *src;
    float a = al[l];
#pragma unroll
    for (int j = 0; j < 8; ++j) s[j] = fmaf(a, (float)h[j], s[j]);
  }
#pragma unroll
  for (int j = 0; j < 8; ++j) tmp[rp][g*8 + j] = s[j];
  __syncthreads();
  float* dst = part + ((size_t)lc * B_DIM + b) * H_DIM + tid*4;
  f32x4 o;
#pragma unroll
  for (int q = 0; q < 4; ++q) o[q] = tmp[0][tid*4 + q] + tmp[1][tid*4 + q];
  *(f32x4*)dst = o;
}

// fallback pool1 on fp32 hs
__global__ __launch_bounds__(256) void pool1_kernel(const float* __restrict__ hs,
                                                    const float* __restrict__ alphas,
                                                    float* __restrict__ part) {
  int b = blockIdx.x >> 3;
  int lc = blockIdx.x & 7;
  int tid = threadIdx.x;
  __shared__ float al[64];
  if (tid < 64) al[tid] = alphas[b * L_DIM + lc*64 + tid];
  __syncthreads();
  const float* xp = hs + ((size_t)b * L_DIM + lc*64) * H_DIM;
  int h0 = tid * 3;
  float s0 = 0.f, s1 = 0.f, s2 = 0.f;
  for (int l = 0; l < 64; ++l) {
    float a = al[l];
    const float* r = xp + (size_t)l * H_DIM + h0;
    s0 += a * r[0]; s1 += a * r[1]; s2 += a * r[2];
  }
  float* dst = part + ((size_t)lc * B_DIM + b) * H_DIM + h0;
  dst[0] = s0; dst[1] = s1; dst[2] = s2;
}

__global__ __launch_bounds__(256) void pool2_kernel(const float* __restrict__ part,
                                                    float* __restrict__ out) {
  int i = blockIdx.x * 256 + threadIdx.x;
  float s = 0.f;
  for (int lc = 0; lc < 8; ++lc) s += part[(size_t)lc * (B_DIM * H_DIM) + i];
  out[i] = s;
}

extern "C" void kernel_launch(void* const* d_in, const int* in_sizes, int n_in,
                              void* d_out, int out_size, void* d_ws, size_t ws_size,
                              hipStream_t stream) {
  const float* hs  = (const float*)d_in[0];
  const float* Wfc = (const float*)d_in[1];
  const float* bfc = (const float*)d_in[2];
  const float* wnu = (const float*)d_in[3];
  float* out = (float*)d_out;
  char* ws = (char*)d_ws;
  _Float16* W16 = (_Float16*)(ws + WS_W16);
  float* nup    = (float*)(ws + WS_NUP);
  float* alphas = (float*)(ws + WS_ALPHA);
  float* part   = (float*)(ws + WS_POOL);

  bool img = (ws_size >= WS_NEED_IMG);
  _Float16* Aimg = (_Float16*)(ws + WS_AIMG);
  if (img) {
    conv_kernel<<<(NB_CNT + MB_CNT) * KB_CNT, 256, 0, stream>>>(Wfc, hs, W16, Aimg);
    gemm_nu_img_kernel<<<MB_CNT * 2, 256, 0, stream>>>(Aimg, W16, bfc, wnu, nup);
  } else {
    conv_kernel<<<NB_CNT * KB_CNT, 256, 0, stream>>>(Wfc, hs, W16, Aimg);
    gemm_nu_kernel<<<MB_CNT * NB_CNT, 256, 0, stream>>>(hs, W16, bfc, wnu, nup);
  }
  softmax_kernel<<<B_DIM, 512, 0, stream>>>(nup, alphas);
  if (img) {
    pool1_img_kernel<<<B_DIM * 8, 192, 0, stream>>>(Aimg, alphas, part);
  } else {
    pool1_kernel<<<B_DIM * 8, 256, 0, stream>>>(hs, alphas, part);
  }
  pool2_kernel<<<192, 256, 0, stream>>>(part, out);
}

// Round 8
// 89.283 us; speedup vs baseline: 1.2229x; 1.0285x over previous
//
#include <hip/hip_runtime.h>

#define H_DIM 768
#define B_DIM 64
#define L_DIM 512
#define M_TOT (B_DIM*L_DIM)   // 32768
#define BM 128
#define BN 128
#define BK 64
#define NB_CNT (H_DIM/BN)     // 6
#define KB_CNT (H_DIM/BK)     // 12
#define MB_CNT (M_TOT/BM)     // 256
#define TILE_HALFS (BM*BK)    // 8192 halfs = 16KB
#define BUFH 16384            // halfs per LDS buffer (A 8192 + B 8192 = 32KB)

typedef _Float16 f16x8 __attribute__((ext_vector_type(8)));
typedef float f32x4 __attribute__((ext_vector_type(4)));

// ws byte offsets
#define WS_W16   0u           // 768*768 halfs (tiled, swizzle-baked)
#define WS_NUP   1179648u     // 6*32768 f32
#define WS_ALPHA 1966080u     // 32768 f32
#define WS_POOL  2097152u     // 8*64*768 f32
#define WS_AIMG  3670016u     // 32768*768 halfs (tiled, swizzle-baked; written by gemm pass 0)
#define WS_NEED_IMG (WS_AIMG + (size_t)M_TOT*H_DIM*2)

__device__ __forceinline__ void gload_lds16(const void* g, void* l) {
  __builtin_amdgcn_global_load_lds((const __attribute__((address_space(1))) void*)g,
                                   (__attribute__((address_space(3))) void*)l, 16, 0, 0);
}

__device__ __forceinline__ f16x8 cvt8(const float* src) {
  f32x4 x0 = *(const f32x4*)src;
  f32x4 x1 = *(const f32x4*)(src + 4);
  f16x8 h;
  h[0]=(_Float16)x0[0]; h[1]=(_Float16)x0[1]; h[2]=(_Float16)x0[2]; h[3]=(_Float16)x0[3];
  h[4]=(_Float16)x1[0]; h[5]=(_Float16)x1[1]; h[6]=(_Float16)x1[2]; h[7]=(_Float16)x1[3];
  return h;
}

__device__ __forceinline__ f16x8 cvt8v(f32x4 x0, f32x4 x1) {
  f16x8 h;
  h[0]=(_Float16)x0[0]; h[1]=(_Float16)x0[1]; h[2]=(_Float16)x0[2]; h[3]=(_Float16)x0[3];
  h[4]=(_Float16)x1[0]; h[5]=(_Float16)x1[1]; h[6]=(_Float16)x1[2]; h[7]=(_Float16)x1[3];
  return h;
}

// tanh(v) = 1 - 2/(exp2(2.885...*v)+1); limits give +-1 exactly.
__device__ __forceinline__ float fast_tanh(float v) {
  float e = __builtin_amdgcn_exp2f(v * 2.8853900817779268f);
  return 1.0f - 2.0f * __builtin_amdgcn_rcpf(e + 1.0f);
}

#define SBAR()  do { __builtin_amdgcn_sched_barrier(0); \
                     __builtin_amdgcn_s_barrier(); \
                     __builtin_amdgcn_sched_barrier(0); } while (0)

// ---------------- kernel 1: W_fc fp32 -> fp16 tiled image (72 blocks only) ----------
__global__ __launch_bounds__(256) void wconv_kernel(const float* __restrict__ Wfc,
                                                    _Float16* __restrict__ W16) {
  int t = blockIdx.x;             // 0..71
  int nb = t / KB_CNT, kb = t % KB_CNT;
#pragma unroll
  for (int i = 0; i < 4; ++i) {
    int u = threadIdx.x + i * 256;
    int row = u >> 3, sp = u & 7;
    int sl = sp ^ (row & 7);
    *(f16x8*)(W16 + (size_t)t*TILE_HALFS + u*8) =
        cvt8(Wfc + (size_t)(nb*BN + row)*H_DIM + kb*BK + sl*8);
  }
}

// ---------------- GEMM helpers ----------------
__device__ __forceinline__ void stage128(const _Float16* at, const _Float16* wt,
                                         _Float16* Lb, int tid) {
#pragma unroll
  for (int i = 0; i < 4; ++i) {
    int e = (tid + i*256) * 8;
    gload_lds16(at + e, Lb + e);
  }
#pragma unroll
  for (int i = 0; i < 4; ++i) {
    int e = (tid + i*256) * 8;
    gload_lds16(wt + e, Lb + 8192 + e);
  }
}

__device__ __forceinline__ void rd_frags(const _Float16* base, const int aoff[4],
                                         const int boff[4], int slot,
                                         f16x8 af[4], f16x8 bf[4]) {
#pragma unroll
  for (int mi = 0; mi < 4; ++mi) af[mi] = *(const f16x8*)(base + aoff[mi] + slot);
#pragma unroll
  for (int ni = 0; ni < 4; ++ni) bf[ni] = *(const f16x8*)(base + boff[ni] + slot);
}

__device__ __forceinline__ void mfma16(const f16x8 af[4], const f16x8 bf[4],
                                       f32x4 acc[4][4]) {
  __builtin_amdgcn_s_setprio(1);
#pragma unroll
  for (int mi = 0; mi < 4; ++mi)
#pragma unroll
    for (int ni = 0; ni < 4; ++ni)
      acc[mi][ni] = __builtin_amdgcn_mfma_f32_16x16x32_f16(af[mi], bf[ni], acc[mi][ni], 0, 0, 0);
  __builtin_amdgcn_s_setprio(0);
}

// One pipelined iteration (passes 1,2). P=1: stage always (j<10 own tile j+2;
// j=10,11 next pass tiles 0,1). P=2: stage only j<10; j=10 drains.
#define PASS_ITER(P, j) do {                                                   \
    _Float16* bufc_ = ((j) & 1) ? b1 : b0;                                     \
    _Float16* bufn_ = ((j) & 1) ? b0 : b1;                                     \
    rd_frags(bufc_, aoff, boff, slot1, af1, bf1);                              \
    mfma16(af0, bf0, acc);                                                     \
    asm volatile("s_waitcnt lgkmcnt(0)" ::: "memory");                         \
    SBAR();                                                                    \
    if ((P) < 2 || (j) < 10) {                                                 \
      const _Float16* aS = abase + (size_t)(((j) < 10) ? (j) + 2 : (j) - 10) * TILE_HALFS; \
      stage128(aS, wS, bufc_, tid);                                            \
      wS += TILE_HALFS;                                                        \
    }                                                                          \
    if ((P) == 2 && (j) == 10) { asm volatile("s_waitcnt vmcnt(0)" ::: "memory"); } \
    else                       { asm volatile("s_waitcnt vmcnt(8)" ::: "memory"); } \
    SBAR();                                                                    \
    rd_frags(bufn_, aoff, boff, slot0, af0, bf0);                              \
    mfma16(af1, bf1, acc);                                                     \
  } while (0)

// Per-pass epilogue: tanh + wnu-dot + LDS-transpose reduction + store.
#define EPI(P) do {                                                            \
    float s16_[4][4];                                                          \
    _Pragma("unroll") for (int mi = 0; mi < 4; ++mi)                           \
    _Pragma("unroll") for (int r = 0; r < 4; ++r) {                            \
      float s_ = 0.f;                                                          \
      _Pragma("unroll") for (int ni = 0; ni < 4; ++ni)                         \
        s_ = fmaf(fast_tanh(acc[mi][ni][r] + bb[P][ni]), wn[P][ni], s_);       \
      s16_[mi][r] = s_;                                                        \
    }                                                                          \
    if (wc == 0) {                                                             \
      _Pragma("unroll") for (int mi = 0; mi < 4; ++mi)                         \
      _Pragma("unroll") for (int r = 0; r < 4; ++r)                            \
        scr[(wr*64 + mi*16 + lk*4 + r)*20 + lrow] = s16_[mi][r];               \
    }                                                                          \
    asm volatile("s_waitcnt lgkmcnt(0)" ::: "memory");                         \
    SBAR();                                                                    \
    float pa_ = 0.f;                                                           \
    if (tid < 128) {                                                           \
      const f32x4* sp_ = (const f32x4*)(scr + tid*20);                         \
      f32x4 q_ = sp_[0] + sp_[1] + sp_[2] + sp_[3];                            \
      pa_ = q_[0] + q_[1] + q_[2] + q_[3];                                     \
    }                                                                          \
    asm volatile("s_waitcnt lgkmcnt(0)" ::: "memory");                         \
    SBAR();                                                                    \
    if (wc == 1) {                                                             \
      _Pragma("unroll") for (int mi = 0; mi < 4; ++mi)                         \
      _Pragma("unroll") for (int r = 0; r < 4; ++r)                            \
        scr[(wr*64 + mi*16 + lk*4 + r)*20 + lrow] = s16_[mi][r];               \
    }                                                                          \
    asm volatile("s_waitcnt lgkmcnt(0)" ::: "memory");                         \
    SBAR();                                                                    \
    if (tid < 128) {                                                           \
      const f32x4* sp_ = (const f32x4*)(scr + tid*20);                         \
      f32x4 q_ = sp_[0] + sp_[1] + sp_[2] + sp_[3];                            \
      nup[(size_t)(nb0 + (P)) * M_TOT + m0 + tid] = pa_ + q_[0]+q_[1]+q_[2]+q_[3]; \
    }                                                                          \
  } while (0)

// ---------------- kernel 2: fused conv+GEMM, 3 nb passes per block ----------------
// Pass 0: A reg-staged from fp32 hs (T14 split), ds_write to LDS + global_store
// fp16 image. Passes 1,2: R6 fine pipeline staging from the image via gload_lds.
__global__ __launch_bounds__(256, 2) void gemm_fused_kernel(const float* __restrict__ hs,
                                                            const _Float16* __restrict__ W16,
                                                            const float* __restrict__ bfc,
                                                            const float* __restrict__ wnu,
                                                            _Float16* __restrict__ Aimg,
                                                            float* __restrict__ nup) {
  __shared__ __align__(16) _Float16 LS[2 * BUFH];         // 64KB double buffer
  __shared__ __align__(16) float scr[128 * 20];           // 10KB reduce scratch

  int bid = blockIdx.x;
  int mb = bid & (MB_CNT - 1);    // 0..255
  int nb0 = (bid >> 8) * 3;       // 0 or 3
  int m0 = mb * BM;
  int tid = threadIdx.x;
  int wv = tid >> 6, ln = tid & 63;
  int wr = wv >> 1, wc = wv & 1;  // 2x2 wave grid, 64x64 output each
  int lrow = ln & 15, lk = ln >> 4;

  f32x4 acc[4][4] = {};
  f16x8 af0[4], bf0[4], af1[4], bf1[4];
  _Float16* imgb = Aimg + (size_t)(mb * KB_CNT) * TILE_HALFS;
  const _Float16* abase = imgb;
  const _Float16* wb0 = W16 + (size_t)(nb0 * KB_CNT) * TILE_HALFS;
  _Float16* b0 = LS;
  _Float16* b1 = LS + BUFH;

  int aoff[4], boff[4];
#pragma unroll
  for (int mi = 0; mi < 4; ++mi) aoff[mi] = (wr*64 + mi*16 + lrow) * 64;
#pragma unroll
  for (int ni = 0; ni < 4; ++ni) boff[ni] = 8192 + (wc*64 + ni*16 + lrow) * 64;
  int slot0 = ((0*4 + lk) ^ (lrow & 7)) * 8;
  int slot1 = ((1*4 + lk) ^ (lrow & 7)) * 8;

  float wn[3][4], bb[3][4];
#pragma unroll
  for (int p = 0; p < 3; ++p)
#pragma unroll
    for (int ni = 0; ni < 4; ++ni) {
      int c = (nb0 + p)*BN + wc*64 + ni*16 + lrow;  // C/D col = lane&15 (m89-verified)
      wn[p][ni] = wnu[c];
      bb[p][ni] = bfc[c];
    }
  asm volatile("s_waitcnt vmcnt(0)" ::: "memory");

  // ================= pass 0: fused convert+GEMM =================
  {
    int r0 = tid >> 3, sp = tid & 7;
    int sl = sp ^ (r0 & 7);                          // same sl for all 4 sub-rows (32 ≡ 0 mod 8)
    const float* asrc = hs + (size_t)(m0 + r0) * H_DIM + sl * 8;
    f32x4 R[8]; f16x8 H[4];
    // prologue: W(0) gloads + A(0) fp32 loads
#pragma unroll
    for (int i = 0; i < 4; ++i) {
      int e = (tid + i*256) * 8;
      gload_lds16(wb0 + e, b0 + 8192 + e);
    }
#pragma unroll
    for (int i = 0; i < 4; ++i) {
      const float* p = asrc + (size_t)(32*i) * H_DIM;
      R[2*i] = *(const f32x4*)p; R[2*i+1] = *(const f32x4*)(p + 4);
    }
#pragma unroll
    for (int i = 0; i < 4; ++i) H[i] = cvt8v(R[2*i], R[2*i+1]);  // data-dep waits loads (W older -> also done)

#pragma unroll 1
    for (int kb = 0; kb < 12; ++kb) {
      _Float16* bufc = (kb & 1) ? b1 : b0;
      _Float16* bufn = (kb & 1) ? b0 : b1;
      _Float16* idst = imgb + (size_t)kb * TILE_HALFS;
      // commit current tile: LDS + image
#pragma unroll
      for (int i = 0; i < 4; ++i) {
        int e = (tid + i*256) * 8;
        *(f16x8*)(bufc + e) = H[i];                  // ds_write_b128
        *(f16x8*)(idst + e) = H[i];                  // global_store (image)
      }
      // issue next tile's W gloads + A fp32 loads (latency hides under MFMA below)
      if (kb < 11) {
#pragma unroll
        for (int i = 0; i < 4; ++i) {
          int e = (tid + i*256) * 8;
          gload_lds16(wb0 + (size_t)(kb+1)*TILE_HALFS + e, bufn + 8192 + e);
        }
        const float* an = asrc + (size_t)(kb+1) * BK;
#pragma unroll
        for (int i = 0; i < 4; ++i) {
          const float* p = an + (size_t)(32*i) * H_DIM;
          R[2*i] = *(const f32x4*)p; R[2*i+1] = *(const f32x4*)(p + 4);
        }
      }
      asm volatile("s_waitcnt lgkmcnt(0)" ::: "memory");  // ds_writes committed
      SBAR();                                             // W(kb) landed (in-order: older than consumed A(kb))
      rd_frags(bufc, aoff, boff, slot0, af0, bf0);
      mfma16(af0, bf0, acc);
      rd_frags(bufc, aoff, boff, slot1, af1, bf1);
      mfma16(af1, bf1, acc);
      if (kb < 11) {
#pragma unroll
        for (int i = 0; i < 4; ++i) H[i] = cvt8v(R[2*i], R[2*i+1]);  // waits A(kb+1)
      }
      SBAR();                                             // protect bufn.B from next iter's gloads
    }
  }

  // ================= transition: prologue of pass 1 under EPI(0) =================
  const _Float16* w1b = W16 + (size_t)((nb0 + 1) * KB_CNT) * TILE_HALFS;
  stage128(abase,              w1b,              b0, tid);
  stage128(abase + TILE_HALFS, w1b + TILE_HALFS, b1, tid);
  const _Float16* wS = w1b + 2 * TILE_HALFS;      // monotonic W stage cursor
  EPI(0);
#pragma unroll
  for (int mi = 0; mi < 4; ++mi)
#pragma unroll
    for (int ni = 0; ni < 4; ++ni) acc[mi][ni] = f32x4{0.f, 0.f, 0.f, 0.f};
  asm volatile("s_waitcnt vmcnt(8)" ::: "memory");  // pass-0 stores + t0 landed (t1's 8 in flight)
  SBAR();
  rd_frags(b0, aoff, boff, slot0, af0, bf0);        // pass-1 t0 kk0

  // ---- pass 1 ----
#pragma unroll 1
  for (int j = 0; j < 12; ++j) PASS_ITER(1, j);
  EPI(1);
#pragma unroll
  for (int mi = 0; mi < 4; ++mi)
#pragma unroll
    for (int ni = 0; ni < 4; ++ni) acc[mi][ni] = f32x4{0.f, 0.f, 0.f, 0.f};

  // ---- pass 2 (last tile peeled) ----
#pragma unroll 1
  for (int j = 0; j < 11; ++j) PASS_ITER(2, j);
  rd_frags(b1, aoff, boff, slot1, af1, bf1);        // t11 kk1
  mfma16(af0, bf0, acc);                            // t11 kk0
  mfma16(af1, bf1, acc);                            // t11 kk1
  EPI(2);
}

// ---------------- fallback GEMM (fp32 A, in-kernel convert, 128^2) ----------------
__global__ __launch_bounds__(256) void gemm_nu_kernel(const float* __restrict__ A,
                                                      const _Float16* __restrict__ W16,
                                                      const float* __restrict__ bfc,
                                                      const float* __restrict__ wnu,
                                                      float* __restrict__ nup) {
  __shared__ __align__(16) _Float16 lsA[TILE_HALFS];
  __shared__ __align__(16) _Float16 lsB[TILE_HALFS];
  __shared__ float nred[2][BM];

  int bid = blockIdx.x;
  int nb = bid % NB_CNT;
  int mb = bid / NB_CNT;
  int m0 = mb * BM, n0 = nb * BN;
  int tid = threadIdx.x;
  int wv = tid >> 6, ln = tid & 63;
  int wr = wv >> 1, wc = wv & 1;
  int lrow = ln & 15, lk = ln >> 4;

  f32x4 acc[4][4] = {};
  const _Float16* wbase = W16 + (size_t)(nb * KB_CNT) * TILE_HALFS;

  for (int kb = 0; kb < KB_CNT; ++kb) {
    const _Float16* wt = wbase + (size_t)kb * TILE_HALFS;
    for (int i = 0; i < 4; ++i) {
      int e = (tid + i*256) * 8;
      gload_lds16(wt + e, lsB + e);
    }
    for (int i = 0; i < 4; ++i) {
      int u = tid + i * 256;
      int row = u >> 3, sl = u & 7;
      *(f16x8*)(lsA + row*BK + ((sl ^ (row & 7)) * 8)) =
          cvt8(A + (size_t)(m0 + row) * H_DIM + kb*BK + sl*8);
    }
    __syncthreads();
#pragma unroll
    for (int kk = 0; kk < 2; ++kk) {
      f16x8 af[4], bf[4];
      int s = kk*4 + lk;
#pragma unroll
      for (int mi = 0; mi < 4; ++mi) {
        int r = wr*64 + mi*16 + lrow;
        af[mi] = *(const f16x8*)(lsA + r*BK + ((s ^ (r & 7)) * 8));
      }
#pragma unroll
      for (int ni = 0; ni < 4; ++ni) {
        int r = wc*64 + ni*16 + lrow;
        bf[ni] = *(const f16x8*)(lsB + r*BK + ((s ^ (r & 7)) * 8));
      }
#pragma unroll
      for (int mi = 0; mi < 4; ++mi)
#pragma unroll
        for (int ni = 0; ni < 4; ++ni)
          acc[mi][ni] = __builtin_amdgcn_mfma_f32_16x16x32_f16(af[mi], bf[ni], acc[mi][ni], 0, 0, 0);
    }
    __syncthreads();
  }

  float wn[4], bb[4];
  for (int ni = 0; ni < 4; ++ni) {
    int c = n0 + wc*64 + ni*16 + lrow;
    wn[ni] = wnu[c];
    bb[ni] = bfc[c];
  }
  for (int mi = 0; mi < 4; ++mi) {
    for (int r = 0; r < 4; ++r) {
      float s = 0.f;
      for (int ni = 0; ni < 4; ++ni)
        s = fmaf(fast_tanh(acc[mi][ni][r] + bb[ni]), wn[ni], s);
      for (int o = 1; o < 16; o <<= 1) s += __shfl_xor(s, o, 64);
      if (lrow == 0) nred[wc][wr*64 + mi*16 + lk*4 + r] = s;
    }
  }
  __syncthreads();
  if (tid < BM)
    nup[(size_t)nb * M_TOT + m0 + tid] = nred[0][tid] + nred[1][tid];
}

// ---------------- kernel 3: softmax over L per batch ----------------
__global__ __launch_bounds__(512) void softmax_kernel(const float* __restrict__ nup,
                                                      float* __restrict__ alphas) {
  int b = blockIdx.x;
  int l = threadIdx.x;
  int m = b * L_DIM + l;
  float v = 0.f;
  for (int nb = 0; nb < NB_CNT; ++nb) v += nup[(size_t)nb * M_TOT + m];
  __shared__ float smax[8], ssum[8];
  int w = l >> 6, ln = l & 63;
  float mx = v;
  for (int o = 1; o < 64; o <<= 1) mx = fmaxf(mx, __shfl_xor(mx, o, 64));
  if (ln == 0) smax[w] = mx;
  __syncthreads();
  mx = smax[0];
  for (int i = 1; i < 8; ++i) mx = fmaxf(mx, smax[i]);
  float e = __expf(v - mx);
  float sm = e;
  for (int o = 1; o < 64; o <<= 1) sm += __shfl_xor(sm, o, 64);
  if (ln == 0) ssum[w] = sm;
  __syncthreads();
  float tot = 0.f;
  for (int i = 0; i < 8; ++i) tot += ssum[i];
  alphas[m] = e / tot;
}

// ---------------- pooling from fp16 A-image ----------------
__global__ __launch_bounds__(192) void pool1_img_kernel(const _Float16* __restrict__ img,
                                                        const float* __restrict__ alphas,
                                                        float* __restrict__ part) {
  int b = blockIdx.x >> 3;
  int lc = blockIdx.x & 7;
  int tid = threadIdx.x;
  int g = tid % 96, rp = tid / 96;
  int kb = g >> 3, sl = g & 7;
  __shared__ float al[64];
  __shared__ float tmp[2][H_DIM];
  if (tid < 64) al[tid] = alphas[b * L_DIM + lc*64 + tid];
  __syncthreads();
  float s[8] = {};
  for (int l = rp; l < 64; l += 2) {
    int m = b * L_DIM + lc*64 + l;
    int mb = m >> 7, row = m & 127;
    const f16x8* src = (const f16x8*)(img + ((size_t)(mb*KB_CNT + kb))*TILE_HALFS
                                      + row*64 + ((sl ^ (row & 7)) * 8));
    f16x8 h = *src;
    float a = al[l];
#pragma unroll
    for (int j = 0; j < 8; ++j) s[j] = fmaf(a, (float)h[j], s[j]);
  }
#pragma unroll
  for (int j = 0; j < 8; ++j) tmp[rp][g*8 + j] = s[j];
  __syncthreads();
  float* dst = part + ((size_t)lc * B_DIM + b) * H_DIM + tid*4;
  f32x4 o;
#pragma unroll
  for (int q = 0; q < 4; ++q) o[q] = tmp[0][tid*4 + q] + tmp[1][tid*4 + q];
  *(f32x4*)dst = o;
}

// fallback pool1 on fp32 hs
__global__ __launch_bounds__(256) void pool1_kernel(const float* __restrict__ hs,
                                                    const float* __restrict__ alphas,
                                                    float* __restrict__ part) {
  int b = blockIdx.x >> 3;
  int lc = blockIdx.x & 7;
  int tid = threadIdx.x;
  __shared__ float al[64];
  if (tid < 64) al[tid] = alphas[b * L_DIM + lc*64 + tid];
  __syncthreads();
  const float* xp = hs + ((size_t)b * L_DIM + lc*64) * H_DIM;
  int h0 = tid * 3;
  float s0 = 0.f, s1 = 0.f, s2 = 0.f;
  for (int l = 0; l < 64; ++l) {
    float a = al[l];
    const float* r = xp + (size_t)l * H_DIM + h0;
    s0 += a * r[0]; s1 += a * r[1]; s2 += a * r[2];
  }
  float* dst = part + ((size_t)lc * B_DIM + b) * H_DIM + h0;
  dst[0] = s0; dst[1] = s1; dst[2] = s2;
}

__global__ __launch_bounds__(256) void pool2_kernel(const float* __restrict__ part,
                                                    float* __restrict__ out) {
  int i = blockIdx.x * 256 + threadIdx.x;
  float s = 0.f;
  for (int lc = 0; lc < 8; ++lc) s += part[(size_t)lc * (B_DIM * H_DIM) + i];
  out[i] = s;
}

extern "C" void kernel_launch(void* const* d_in, const int* in_sizes, int n_in,
                              void* d_out, int out_size, void* d_ws, size_t ws_size,
                              hipStream_t stream) {
  const float* hs  = (const float*)d_in[0];
  const float* Wfc = (const float*)d_in[1];
  const float* bfc = (const float*)d_in[2];
  const float* wnu = (const float*)d_in[3];
  float* out = (float*)d_out;
  char* ws = (char*)d_ws;
  _Float16* W16 = (_Float16*)(ws + WS_W16);
  float* nup    = (float*)(ws + WS_NUP);
  float* alphas = (float*)(ws + WS_ALPHA);
  float* part   = (float*)(ws + WS_POOL);

  bool img = (ws_size >= WS_NEED_IMG);
  _Float16* Aimg = (_Float16*)(ws + WS_AIMG);
  wconv_kernel<<<NB_CNT * KB_CNT, 256, 0, stream>>>(Wfc, W16);
  if (img) {
    gemm_fused_kernel<<<MB_CNT * 2, 256, 0, stream>>>(hs, W16, bfc, wnu, Aimg, nup);
  } else {
    gemm_nu_kernel<<<MB_CNT * NB_CNT, 256, 0, stream>>>(hs, W16, bfc, wnu, nup);
  }
  softmax_kernel<<<B_DIM, 512, 0, stream>>>(nup, alphas);
  if (img) {
    pool1_img_kernel<<<B_DIM * 8, 192, 0, stream>>>(Aimg, alphas, part);
  } else {
    pool1_kernel<<<B_DIM * 8, 256, 0, stream>>>(hs, alphas, part);
  }
  pool2_kernel<<<192, 256, 0, stream>>>(part, out);
}